// Round 8
// baseline (780.188 us; speedup 1.0000x reference)
//
#include <hip/hip_runtime.h>
#include <math.h>

#define DIMD    1024
#define MLPD    4096
#define DSTATE  16
#define DCONV   4
#define HALF    1024
#define DINNER  2048
#define DTRANK  64
#define BSZ     2
#define SEQ     2048
#define NTOK    (BSZ*SEQ)   // 4096
#define NCH     64
#define CL      (SEQ/NCH)   // 32

typedef short bf16x8 __attribute__((ext_vector_type(8)));
typedef float f32x4  __attribute__((ext_vector_type(4)));
typedef float f32x16 __attribute__((ext_vector_type(16)));
typedef unsigned short u16;
typedef unsigned int   u32;
typedef unsigned short u16x4 __attribute__((ext_vector_type(4)));

__device__ __forceinline__ u16 f2bf(float x) {
    union { float f; unsigned int u; } v; v.f = x;
    unsigned int r = (v.u + 0x7FFFu + ((v.u >> 16) & 1u)) >> 16;
    return (u16)r;
}
__device__ __forceinline__ float bf2f(u16 x) {
    union { unsigned int u; float f; } v; v.u = ((unsigned int)x) << 16;
    return v.f;
}

// ------- fused LN1 + residual-init (x2 = x) + weight f32->bf16 convert ---
#define SZ_WIN  (DINNER*DIMD)
#define SZ_WXP  (96*HALF)
#define SZ_WDT  (HALF*DTRANK)
#define SZ_WOUT (DIMD*DINNER)
#define SZ_WM1  (MLPD*DIMD)
#define SZ_WM2  (DIMD*MLPD)
#define SZ_TOT  (SZ_WIN+SZ_WXP+SZ_WDT+SZ_WOUT+SZ_WM1+SZ_WM2)
#define CVT_BLOCKS (SZ_TOT / 1024)

__global__ __launch_bounds__(256) void cvtln_kernel(
        const float* __restrict__ x, const float* __restrict__ g,
        const float* __restrict__ b, u16* __restrict__ xn_bf,
        float* __restrict__ x2,
        const float* __restrict__ s0, u16* __restrict__ d0,
        const float* __restrict__ s1, u16* __restrict__ d1,
        const float* __restrict__ s2, u16* __restrict__ d2,
        const float* __restrict__ s3, u16* __restrict__ d3,
        const float* __restrict__ s4, u16* __restrict__ d4,
        const float* __restrict__ s5, u16* __restrict__ d5) {
    if (blockIdx.x >= NTOK) {
        int i = (blockIdx.x - NTOK) * 1024 + threadIdx.x * 4;
        #define CVT4(s, d) { \
            float4 v = *(const float4*)((s) + i); \
            u16x4 o; o[0]=f2bf(v.x); o[1]=f2bf(v.y); o[2]=f2bf(v.z); o[3]=f2bf(v.w); \
            *(u16x4*)((d) + i) = o; }
        if (i < SZ_WIN)  { CVT4(s0, d0); return; }  i -= SZ_WIN;
        if (i < SZ_WXP)  { CVT4(s1, d1); return; }  i -= SZ_WXP;
        if (i < SZ_WDT)  { CVT4(s2, d2); return; }  i -= SZ_WDT;
        if (i < SZ_WOUT) { CVT4(s3, d3); return; }  i -= SZ_WOUT;
        if (i < SZ_WM1)  { CVT4(s4, d4); return; }  i -= SZ_WM1;
        if (i < SZ_WM2)  { CVT4(s5, d5); }
        #undef CVT4
        return;
    }
    __shared__ float sm[4];
    int row = blockIdx.x;
    int t = threadIdx.x;
    size_t base = (size_t)row * DIMD + t * 4;
    const float4* xr = (const float4*)(x + (size_t)row * DIMD);
    float4 v = xr[t];
    // residual init for out_proj's atomic accumulation: x2 = x
    *(float4*)(x2 + base) = v;
    float s = v.x + v.y + v.z + v.w;
    for (int off = 32; off > 0; off >>= 1) s += __shfl_down(s, off, 64);
    if ((t & 63) == 0) sm[t >> 6] = s;
    __syncthreads();
    float mu = (sm[0] + sm[1] + sm[2] + sm[3]) * (1.0f / DIMD);
    float dx = v.x - mu, dy = v.y - mu, dz = v.z - mu, dw = v.w - mu;
    float ss = dx*dx + dy*dy + dz*dz + dw*dw;
    for (int off = 32; off > 0; off >>= 1) ss += __shfl_down(ss, off, 64);
    __syncthreads();
    if ((t & 63) == 0) sm[t >> 6] = ss;
    __syncthreads();
    float var = (sm[0] + sm[1] + sm[2] + sm[3]) * (1.0f / DIMD);
    float rs = rsqrtf(var + 1e-5f);
    float4 gv = ((const float4*)g)[t];
    float4 bv = ((const float4*)b)[t];
    u16* o = xn_bf + base;
    o[0] = f2bf(dx * rs * gv.x + bv.x);
    o[1] = f2bf(dy * rs * gv.y + bv.y);
    o[2] = f2bf(dz * rs * gv.z + bv.z);
    o[3] = f2bf(dw * rs * gv.w + bv.w);
}

// ---------------- x_proj GEMM: 4 waves = 2 m-tiles x 2 K-halves ----------
__global__ __launch_bounds__(256) void gemm_small_kernel(
        const u16* __restrict__ A, int lda,
        const u16* __restrict__ W, int K, int N,
        float* __restrict__ Cf, u16* __restrict__ Cb) {
    __shared__ f32x4 red[2][64];
    int t = threadIdx.x;
    int w = t >> 6, lane = t & 63;
    int mt = w & 1, kh = w >> 1;
    int m0 = blockIdx.x * 32 + mt * 16;
    int n0 = blockIdx.y * 16;
    int r = lane & 15, quad = lane >> 4;
    int Kh = K >> 1;
    f32x4 acc = {0.f, 0.f, 0.f, 0.f};
    const u16* ap = A + (size_t)(m0 + r) * lda + kh * Kh + quad * 8;
    const u16* wp = W + (size_t)(n0 + r) * K   + kh * Kh + quad * 8;
    for (int k = 0; k < Kh; k += 32) {
        bf16x8 av = *(const bf16x8*)(ap + k);
        bf16x8 bv = *(const bf16x8*)(wp + k);
        acc = __builtin_amdgcn_mfma_f32_16x16x32_bf16(av, bv, acc, 0, 0, 0);
    }
    if (kh == 1) red[mt][lane] = acc;
    __syncthreads();
    if (kh == 0) {
        f32x4 o = red[mt][lane];
        int col = n0 + r;
        #pragma unroll
        for (int i = 0; i < 4; ++i) {
            int row = m0 + quad * 4 + i;
            size_t idx = (size_t)row * N + col;
            float v = acc[i] + o[i];
            Cf[idx] = v;
            Cb[idx] = f2bf(v);
        }
    }
}

// ---------------- 2-phase 128xTN GEMM (in_proj / dt_proj) ----------------
// EPI: 1 bias+softplus f32 | 5 plain bf16
template<int EPI, int TN, int KS>
__global__ __launch_bounds__(256) void gemm128_kernel(
        const u16* __restrict__ A, int lda, const u16* __restrict__ W,
        int K, int N,
        const float* __restrict__ bias, const float* __restrict__ resid,
        float* __restrict__ Cf, float* __restrict__ Cf2,
        float* __restrict__ Cf3, float* __restrict__ Cf4,
        u16* __restrict__ Cb) {
    constexpr int NF = TN / 32;
    constexpr int NN = TN / 64;
    __shared__ u16 As0[128 * 32], As1[128 * 32];
    __shared__ u16 Bs0[TN * 32],  Bs1[TN * 32];
    const int t = threadIdx.x;
    const int w = t >> 6;
    const int lane = t & 63;
    const int r32 = lane & 31;
    const int kh  = lane >> 5;
    const int wm = w & 1, wn = w >> 1;
    const int m0 = blockIdx.x * 128;
    const int n0 = blockIdx.y * TN;
    const int Kloc = K / KS;
    const int kz = (KS > 1) ? blockIdx.z : 0;

    f32x16 acc[2][NN];
    #pragma unroll
    for (int mi = 0; mi < 2; ++mi)
        #pragma unroll
        for (int ni = 0; ni < NN; ++ni)
            acc[mi][ni] = (f32x16){0.f,0.f,0.f,0.f,0.f,0.f,0.f,0.f,
                                   0.f,0.f,0.f,0.f,0.f,0.f,0.f,0.f};

    const u16* pa[2];
    const u16* pb[NF / 2];
    #pragma unroll
    for (int i = 0; i < 2; ++i) {
        int c = (i * 4 + w) * 64 + lane;
        int row = c >> 2;
        int q = (c & 3) ^ ((row >> 1) & 3);
        pa[i] = A + (size_t)(m0 + row) * lda + (size_t)kz * Kloc + q * 8;
    }
    #pragma unroll
    for (int i = 0; i < NF / 2; ++i) {
        int c = (i * 4 + w) * 64 + lane;
        int row = c >> 2;
        int q = (c & 3) ^ ((row >> 1) & 3);
        pb[i] = W + (size_t)(n0 + row) * K + (size_t)kz * Kloc + q * 8;
    }
    const int gsw = (r32 >> 1) & 3;
    int aoff[2][2], boff[NN][2];
    #pragma unroll
    for (int mi = 0; mi < 2; ++mi)
        #pragma unroll
        for (int tt = 0; tt < 2; ++tt)
            aoff[mi][tt] = (wm * 64 + mi * 32 + r32) * 32 +
                           ((tt * 2 + kh) ^ gsw) * 8;
    #pragma unroll
    for (int ni = 0; ni < NN; ++ni)
        #pragma unroll
        for (int tt = 0; tt < 2; ++tt)
            boff[ni][tt] = (wn * (TN / 2) + ni * 32 + r32) * 32 +
                           ((tt * 2 + kh) ^ gsw) * 8;

    auto stage = [&](u16* __restrict__ Ad, u16* __restrict__ Bd) {
        #pragma unroll
        for (int i = 0; i < 2; ++i) {
            __builtin_amdgcn_global_load_lds(
                (const __attribute__((address_space(1))) u32*)pa[i],
                (__attribute__((address_space(3))) u32*)(Ad + (i * 4 + w) * 512),
                16, 0, 0);
            pa[i] += 32;
        }
        #pragma unroll
        for (int i = 0; i < NF / 2; ++i) {
            __builtin_amdgcn_global_load_lds(
                (const __attribute__((address_space(1))) u32*)pb[i],
                (__attribute__((address_space(3))) u32*)(Bd + (i * 4 + w) * 512),
                16, 0, 0);
            pb[i] += 32;
        }
    };
    auto compute = [&](const u16* __restrict__ Ab, const u16* __restrict__ Bb) {
        bf16x8 af[2][2], bfr[NN][2];
        #pragma unroll
        for (int mi = 0; mi < 2; ++mi)
            #pragma unroll
            for (int tt = 0; tt < 2; ++tt)
                af[mi][tt] = *(const bf16x8*)(Ab + aoff[mi][tt]);
        #pragma unroll
        for (int ni = 0; ni < NN; ++ni)
            #pragma unroll
            for (int tt = 0; tt < 2; ++tt)
                bfr[ni][tt] = *(const bf16x8*)(Bb + boff[ni][tt]);
        #pragma unroll
        for (int tt = 0; tt < 2; ++tt)
            #pragma unroll
            for (int mi = 0; mi < 2; ++mi)
                #pragma unroll
                for (int ni = 0; ni < NN; ++ni)
                    acc[mi][ni] = __builtin_amdgcn_mfma_f32_32x32x16_bf16(
                        af[mi][tt], bfr[ni][tt], acc[mi][ni], 0, 0, 0);
    };

    stage(As0, Bs0);
    for (int k0 = 0; k0 < Kloc; k0 += 64) {
        __syncthreads();
        if (k0 + 32 < Kloc) stage(As1, Bs1);
        compute(As0, Bs0);
        __syncthreads();
        if (k0 + 64 < Kloc) stage(As0, Bs0);
        compute(As1, Bs1);
    }

    float* Cfo = Cf;
    if (KS == 2 && kz == 1) Cfo = Cf2;
    if (KS == 4) Cfo = (kz == 0) ? Cf : (kz == 1) ? Cf2 : (kz == 2) ? Cf3 : Cf4;
    #pragma unroll
    for (int mi = 0; mi < 2; ++mi) {
        #pragma unroll
        for (int ni = 0; ni < NN; ++ni) {
            #pragma unroll
            for (int reg = 0; reg < 16; ++reg) {
                int row = m0 + wm * 64 + mi * 32 + (reg & 3) + 8 * (reg >> 2) + 4 * kh;
                int col = n0 + wn * (TN / 2) + ni * 32 + r32;
                size_t idx = (size_t)row * N + col;
                float v = acc[mi][ni][reg];
                if (EPI == 1) { v += bias[col]; v = (v > 20.f) ? v : log1pf(expf(v)); }
                if (EPI == 2) {
                    v += bias[col];
                    float e = __expf(fminf(1.5957691216f * v + 0.0713548162f * v * v * v, 80.f));
                    v = v * __fdividef(e, e + 1.f);
                }
                if (EPI == 3) { v += resid[idx]; }
                if (EPI == 4) { v += bias[col] + resid[idx]; }
                if (EPI == 2 || EPI == 5) Cb[idx] = f2bf(v);
                else                      Cfo[idx] = v;
            }
        }
    }
}

// ---------------- 8-phase 256x256 GEMM (MLP1 / MLP2 / out_proj) ----------
// 512 threads = 8 waves (2M x 4N); BK=64; XOR-swizzled LDS double-buffer;
// counted vmcnt(2) at phases 3/7; coalesced epilogue via per-wave LDS
// transpose.  EPI: 0 f32 partial (split-K) | 2 bias+gelu -> bf16
//              | 6 f32 atomicAdd into Cf (split-K accumulate in-place)
template<int EPI, int KS_>
__global__ __launch_bounds__(512) void gemm256_kernel(
        const u16* __restrict__ A, int lda, const u16* __restrict__ W,
        int K, int N,
        const float* __restrict__ bias,
        float* __restrict__ Cf, float* __restrict__ Cf2,
        float* __restrict__ Cf3, float* __restrict__ Cf4,
        u16* __restrict__ Cb) {
    __shared__ u16 As[2][256 * 64];   // [buf][row*64 + swizzled col]
    __shared__ u16 Bs[2][256 * 64];
    const int t = threadIdx.x;
    const int lane = t & 63;
    const int w = t >> 6;
    const int r = lane & 15, q = lane >> 4;
    const int wm = w >> 2, wn = w & 3;           // 2 x 4 wave grid
    const int m0 = blockIdx.x * 256;
    const int n0 = blockIdx.y * 256;
    const int kz = (KS_ > 1) ? blockIdx.z : 0;
    const int Kloc = K / KS_;
    const int NI = Kloc / 128;                   // iters (2 K-tiles of 64 each)

    f32x4 acc[8][4];
    #pragma unroll
    for (int mi = 0; mi < 8; ++mi)
        #pragma unroll
        for (int ni = 0; ni < 4; ++ni)
            acc[mi][ni] = (f32x4){0.f, 0.f, 0.f, 0.f};

    const int aoffb = (wm * 128 + r) * 64;
    const int boffb = (wn * 64  + r) * 64;
    const int kswz[2] = { ((0 + q) ^ (r & 7)) * 8,
                          ((4 + q) ^ (r & 7)) * 8 };
    const int srow = t >> 3;
    const int scol = (((t & 7) ^ (srow & 7)) * 8);
    const int sdst = (t >> 6) * 512;
    const size_t kzoff = (size_t)kz * Kloc;

    auto stA = [&](int buf, int T, int j) {
        const u16* src = A + (size_t)(m0 + j * 64 + srow) * lda + kzoff + T * 64 + scol;
        __builtin_amdgcn_global_load_lds(
            (const __attribute__((address_space(1))) u32*)src,
            (__attribute__((address_space(3))) u32*)(&As[buf][j * 4096 + sdst]),
            16, 0, 0);
    };
    auto stB = [&](int buf, int T, int j) {
        const u16* src = W + (size_t)(n0 + j * 64 + srow) * (size_t)K + kzoff + T * 64 + scol;
        __builtin_amdgcn_global_load_lds(
            (const __attribute__((address_space(1))) u32*)src,
            (__attribute__((address_space(3))) u32*)(&Bs[buf][j * 4096 + sdst]),
            16, 0, 0);
    };

    bf16x8 bfr[4];

    #define PH(BUF, KSL, MH, STMT, VMODE)                                         \
    do {                                                                          \
        if (MH == 0) {                                                            \
            _Pragma("unroll")                                                     \
            for (int ni = 0; ni < 4; ++ni)                                        \
                bfr[ni] = *(const bf16x8*)(&Bs[BUF][boffb + ni * 1024 + kswz[KSL]]); \
        }                                                                         \
        bf16x8 af0 = *(const bf16x8*)(&As[BUF][aoffb + (MH*4+0)*1024 + kswz[KSL]]);  \
        bf16x8 af1 = *(const bf16x8*)(&As[BUF][aoffb + (MH*4+1)*1024 + kswz[KSL]]);  \
        bf16x8 af2 = *(const bf16x8*)(&As[BUF][aoffb + (MH*4+2)*1024 + kswz[KSL]]);  \
        bf16x8 af3 = *(const bf16x8*)(&As[BUF][aoffb + (MH*4+3)*1024 + kswz[KSL]]);  \
        STMT;                                                                     \
        VMODE;                                                                    \
        __builtin_amdgcn_s_barrier();                                             \
        asm volatile("s_waitcnt lgkmcnt(0)" ::: "memory");                        \
        __builtin_amdgcn_sched_barrier(0);                                        \
        __builtin_amdgcn_s_setprio(1);                                            \
        _Pragma("unroll")                                                         \
        for (int ni = 0; ni < 4; ++ni) {                                          \
            acc[MH*4+0][ni] = __builtin_amdgcn_mfma_f32_16x16x32_bf16(af0, bfr[ni], acc[MH*4+0][ni], 0, 0, 0); \
            acc[MH*4+1][ni] = __builtin_amdgcn_mfma_f32_16x16x32_bf16(af1, bfr[ni], acc[MH*4+1][ni], 0, 0, 0); \
            acc[MH*4+2][ni] = __builtin_amdgcn_mfma_f32_16x16x32_bf16(af2, bfr[ni], acc[MH*4+2][ni], 0, 0, 0); \
            acc[MH*4+3][ni] = __builtin_amdgcn_mfma_f32_16x16x32_bf16(af3, bfr[ni], acc[MH*4+3][ni], 0, 0, 0); \
        }                                                                         \
        __builtin_amdgcn_s_setprio(0);                                            \
        __builtin_amdgcn_s_barrier();                                             \
    } while (0)

    #define VM_NONE do {} while (0)
    #define VM_P3   do { if (more) asm volatile("s_waitcnt vmcnt(2)" ::: "memory"); \
                         else      asm volatile("s_waitcnt vmcnt(0)" ::: "memory"); } while (0)
    #define VM_P7   do { if (more) asm volatile("s_waitcnt vmcnt(2)" ::: "memory"); } while (0)

    #pragma unroll
    for (int j = 0; j < 4; ++j) stB(0, 0, j);
    #pragma unroll
    for (int j = 0; j < 4; ++j) stA(0, 0, j);
    stB(1, 1, 0); stB(1, 1, 1);
    asm volatile("s_waitcnt vmcnt(2)" ::: "memory");
    __builtin_amdgcn_s_barrier();

    for (int it = 0; it < NI; ++it) {
        const bool more = (it + 1) < NI;
        const int T1 = 2 * it + 1, T2 = T1 + 1, T3 = T1 + 2;
        PH(0, 0, 0, { stB(1, T1, 2); stB(1, T1, 3); }, VM_NONE);
        PH(0, 0, 1, { stA(1, T1, 0); stA(1, T1, 1); }, VM_NONE);
        PH(0, 1, 0, { stA(1, T1, 2); stA(1, T1, 3); }, VM_NONE);
        PH(0, 1, 1, { if (more) { stB(0, T2, 0); stB(0, T2, 1); } }, VM_P3);
        PH(1, 0, 0, { if (more) { stB(0, T2, 2); stB(0, T2, 3); } }, VM_NONE);
        PH(1, 0, 1, { if (more) { stA(0, T2, 0); stA(0, T2, 1); } }, VM_NONE);
        PH(1, 1, 0, { if (more) { stA(0, T2, 2); stA(0, T2, 3); } }, VM_NONE);
        PH(1, 1, 1, { if (more) { stB(1, T3, 0); stB(1, T3, 1); } }, VM_P7);
    }
    #undef PH
    #undef VM_NONE
    #undef VM_P3
    #undef VM_P7

    // ---- coalesced epilogue via per-wave LDS transpose ----
    float* wsc = ((float*)&As[0][0]) + (size_t)w * (16 * 68);
    const int erow = lane >> 3;          // 0..7
    const int ecol = (lane & 7) * 4;     // 0,4,..,28
    float* Cfo = Cf;
    if (EPI == 0 && KS_ == 4)
        Cfo = (kz == 0) ? Cf : (kz == 1) ? Cf2 : (kz == 2) ? Cf3 : Cf4;
    #pragma unroll
    for (int mi = 0; mi < 8; ++mi) {
        #pragma unroll
        for (int ni = 0; ni < 4; ++ni)
            #pragma unroll
            for (int i = 0; i < 4; ++i)
                wsc[(q * 4 + i) * 68 + ni * 16 + r] = acc[mi][ni][i];
        asm volatile("s_waitcnt lgkmcnt(0)" ::: "memory");
        __builtin_amdgcn_sched_barrier(0);
        #pragma unroll
        for (int half = 0; half < 2; ++half) {
            #pragma unroll
            for (int k2 = 0; k2 < 2; ++k2) {
                int lr = half * 8 + erow;
                f32x4 v4 = *(const f32x4*)&wsc[lr * 68 + ecol + k2 * 32];
                int row = m0 + wm * 128 + mi * 16 + lr;
                int colb = n0 + wn * 64 + ecol + k2 * 32;
                size_t idx = (size_t)row * N + colb;
                if (EPI == 2) {
                    float4 bb = *(const float4*)&bias[colb];
                    float vv0 = v4[0] + bb.x, vv1 = v4[1] + bb.y;
                    float vv2 = v4[2] + bb.z, vv3 = v4[3] + bb.w;
                    u16x4 o;
                    #define GELU1(vx, slot) { \
                        float e = __expf(fminf(1.5957691216f * (vx) + 0.0713548162f * (vx)*(vx)*(vx), 80.f)); \
                        o[slot] = f2bf((vx) * __fdividef(e, e + 1.f)); }
                    GELU1(vv0, 0); GELU1(vv1, 1); GELU1(vv2, 2); GELU1(vv3, 3);
                    #undef GELU1
                    *(u16x4*)&Cb[idx] = o;
                } else if (EPI == 6) {
                    atomicAdd(&Cf[idx + 0], v4[0]);
                    atomicAdd(&Cf[idx + 1], v4[1]);
                    atomicAdd(&Cf[idx + 2], v4[2]);
                    atomicAdd(&Cf[idx + 3], v4[3]);
                } else {
                    *(f32x4*)&Cfo[idx] = v4;
                }
            }
        }
        asm volatile("s_waitcnt lgkmcnt(0)" ::: "memory");
        __builtin_amdgcn_sched_barrier(0);
    }
}

// ---------------- slim LN2 + MLP2-output init ----------------------------
// x2 already = x + mixer (via atomics). ln2_bf = LN(x2)*g + b ;
// outpre = x2 + b2  (MLP2 then atomically adds into outpre)
__global__ __launch_bounds__(256) void ln_kernel(
        const float* __restrict__ x2,
        const float* __restrict__ g, const float* __restrict__ b,
        const float* __restrict__ b2,
        u16* __restrict__ out_bf, float* __restrict__ outpre) {
    __shared__ float sm[4];
    int row = blockIdx.x;
    int t = threadIdx.x;
    size_t base = (size_t)row * DIMD + t * 4;
    float4 v = *(const float4*)(x2 + base);
    float4 b2v = ((const float4*)b2)[t];
    float4 op;
    op.x = v.x + b2v.x; op.y = v.y + b2v.y;
    op.z = v.z + b2v.z; op.w = v.w + b2v.w;
    *(float4*)(outpre + base) = op;
    float s = v.x + v.y + v.z + v.w;
    for (int off = 32; off > 0; off >>= 1) s += __shfl_down(s, off, 64);
    if ((t & 63) == 0) sm[t >> 6] = s;
    __syncthreads();
    float mu = (sm[0] + sm[1] + sm[2] + sm[3]) * (1.0f / DIMD);
    float dx = v.x - mu, dy = v.y - mu, dz = v.z - mu, dw = v.w - mu;
    float ss = dx*dx + dy*dy + dz*dz + dw*dw;
    for (int off = 32; off > 0; off >>= 1) ss += __shfl_down(ss, off, 64);
    __syncthreads();
    if ((t & 63) == 0) sm[t >> 6] = ss;
    __syncthreads();
    float var = (sm[0] + sm[1] + sm[2] + sm[3]) * (1.0f / DIMD);
    float rs = rsqrtf(var + 1e-5f);
    float4 gv = ((const float4*)g)[t];
    float4 bv = ((const float4*)b)[t];
    u16* o = out_bf + base;
    o[0] = f2bf(dx * rs * gv.x + bv.x);
    o[1] = f2bf(dy * rs * gv.y + bv.y);
    o[2] = f2bf(dz * rs * gv.z + bv.z);
    o[3] = f2bf(dw * rs * gv.w + bv.w);
}

// ---------------- depthwise conv + SiLU, sliding window (8 l / thread) ---
__global__ __launch_bounds__(256) void conv_silu_kernel(
        const u16* __restrict__ xz,
        const float* __restrict__ wx, const float* __restrict__ bx,
        const float* __restrict__ wz, const float* __restrict__ bz,
        u16* __restrict__ u_bf, u16* __restrict__ ycat) {
    int c  = blockIdx.x * 256 + threadIdx.x;   // 0..1023
    int gy = blockIdx.y;                       // 0..NTOK/8-1
    int b  = gy >> 8;
    int l0 = (gy & 255) * 8;
    const u16* base = xz + ((size_t)(b * SEQ + l0)) * DINNER;
    float wxr[4], wzr[4];
    #pragma unroll
    for (int k = 0; k < 4; ++k) { wxr[k] = wx[c * 4 + k]; wzr[k] = wz[c * 4 + k]; }
    float bxv = bx[c], bzv = bz[c];
    float xm1 = (l0 > 0) ? bf2f(base[c - DINNER]) : 0.f;
    float x0v = bf2f(base[c]);
    float x1v = bf2f(base[c + DINNER]);
    float zm1 = (l0 > 0) ? bf2f(base[HALF + c - DINNER]) : 0.f;
    float z0v = bf2f(base[HALF + c]);
    float z1v = bf2f(base[HALF + c + DINNER]);
    u16* up = u_bf + ((size_t)(b * SEQ + l0)) * HALF + c;
    u16* yp = ycat + ((size_t)(b * SEQ + l0)) * DINNER + HALF + c;
    #pragma unroll
    for (int l = 0; l < 8; ++l) {
        bool in = (l0 + l + 2) < SEQ;
        float x2v = in ? bf2f(base[(size_t)(l + 2) * DINNER + c]) : 0.f;
        float z2v = in ? bf2f(base[(size_t)(l + 2) * DINNER + HALF + c]) : 0.f;
        float ax = bxv + wxr[0]*xm1 + wxr[1]*x0v + wxr[2]*x1v + wxr[3]*x2v;
        float az = bzv + wzr[0]*zm1 + wzr[1]*z0v + wzr[2]*z1v + wzr[3]*z2v;
        float sx = ax * __fdividef(1.f, 1.f + __expf(-ax));
        float sz = az * __fdividef(1.f, 1.f + __expf(-az));
        *up = f2bf(sx); *yp = f2bf(sz);
        up += HALF; yp += DINNER;
        xm1 = x0v; x0v = x1v; x1v = x2v;
        zm1 = z0v; z0v = z1v; z1v = z2v;
    }
}

// ---------------- chunk-parallel selective scan (thread per chain) -------
__global__ __launch_bounds__(256) void scan_p1_kernel(
        const float* __restrict__ delta, const u16* __restrict__ u_bf,
        const float* __restrict__ x_dbl, const float* __restrict__ A_log,
        float* __restrict__ hfin, float* __restrict__ dsum) {
    int t  = blockIdx.x * 256 + threadIdx.x;
    int d  = t & (HALF - 1);
    int ch = (t >> 10) & (NCH - 1);
    int b  = t >> 16;
    float Ac[16], h[16];
    #pragma unroll
    for (int i = 0; i < 4; ++i) {
        float4 a = *(const float4*)&A_log[d * DSTATE + i * 4];
        Ac[4*i+0] = -__expf(a.x); Ac[4*i+1] = -__expf(a.y);
        Ac[4*i+2] = -__expf(a.z); Ac[4*i+3] = -__expf(a.w);
        h[4*i+0] = 0.f; h[4*i+1] = 0.f; h[4*i+2] = 0.f; h[4*i+3] = 0.f;
    }
    int l0 = b * SEQ + ch * CL;
    size_t off = (size_t)l0 * HALF + d;
    const float* xrow = x_dbl + (size_t)l0 * 96;
    float ds = 0.f;
    #pragma unroll 4
    for (int l = 0; l < CL; ++l) {
        float dl = delta[off];
        float uv = bf2f(u_bf[off]);
        off += HALF;
        float4 B0 = *(const float4*)(xrow + 64);
        float4 B1 = *(const float4*)(xrow + 68);
        float4 B2 = *(const float4*)(xrow + 72);
        float4 B3 = *(const float4*)(xrow + 76);
        xrow += 96;
        float dBu = dl * uv;
        ds += dl;
        float Bv[16] = {B0.x,B0.y,B0.z,B0.w, B1.x,B1.y,B1.z,B1.w,
                        B2.x,B2.y,B2.z,B2.w, B3.x,B3.y,B3.z,B3.w};
        #pragma unroll
        for (int n = 0; n < 16; ++n)
            h[n] = __expf(dl * Ac[n]) * h[n] + dBu * Bv[n];
    }
    float4* hf = (float4*)&hfin[(size_t)t * 16];
    #pragma unroll
    for (int i = 0; i < 4; ++i)
        hf[i] = (float4){h[4*i+0], h[4*i+1], h[4*i+2], h[4*i+3]};
    dsum[t] = ds;
}

__global__ __launch_bounds__(256) void scan_p2_kernel(
        const float* __restrict__ A_log, const float* __restrict__ dsum,
        const float* __restrict__ hfin, float* __restrict__ hin) {
    int t = blockIdx.x * 256 + threadIdx.x;
    int n = t & 15;
    int d = (t >> 4) & (HALF - 1);
    int b = t >> 14;
    float Ac = -__expf(A_log[d * DSTATE + n]);
    float h = 0.f;
    for (int ch = 0; ch < NCH; ++ch) {
        size_t chain = ((size_t)(b * NCH + ch) * HALF) + d;
        hin[chain * 16 + n] = h;
        float ds = dsum[chain];
        h = __expf(Ac * ds) * h + hfin[chain * 16 + n];
    }
}

__global__ __launch_bounds__(256) void scan_p3_kernel(
        const float* __restrict__ delta, const u16* __restrict__ u_bf,
        const float* __restrict__ x_dbl, const float* __restrict__ A_log,
        const float* __restrict__ Dp, const float* __restrict__ hin,
        u16* __restrict__ ycat) {
    int t  = blockIdx.x * 256 + threadIdx.x;
    int d  = t & (HALF - 1);
    int ch = (t >> 10) & (NCH - 1);
    int b  = t >> 16;
    float Ac[16], h[16];
    #pragma unroll
    for (int i = 0; i < 4; ++i) {
        float4 a  = *(const float4*)&A_log[d * DSTATE + i * 4];
        float4 hv = *(const float4*)&hin[(size_t)t * 16 + i * 4];
        Ac[4*i+0] = -__expf(a.x); Ac[4*i+1] = -__expf(a.y);
        Ac[4*i+2] = -__expf(a.z); Ac[4*i+3] = -__expf(a.w);
        h[4*i+0] = hv.x; h[4*i+1] = hv.y; h[4*i+2] = hv.z; h[4*i+3] = hv.w;
    }
    float Dv = Dp[d];
    int l0 = b * SEQ + ch * CL;
    size_t off = (size_t)l0 * HALF + d;
    const float* xrow = x_dbl + (size_t)l0 * 96;
    u16* yp = ycat + (size_t)l0 * DINNER + d;
    #pragma unroll 4
    for (int l = 0; l < CL; ++l) {
        float dl = delta[off];
        float uv = bf2f(u_bf[off]);
        off += HALF;
        float4 B0 = *(const float4*)(xrow + 64);
        float4 B1 = *(const float4*)(xrow + 68);
        float4 B2 = *(const float4*)(xrow + 72);
        float4 B3 = *(const float4*)(xrow + 76);
        float4 C0 = *(const float4*)(xrow + 80);
        float4 C1 = *(const float4*)(xrow + 84);
        float4 C2 = *(const float4*)(xrow + 88);
        float4 C3 = *(const float4*)(xrow + 92);
        xrow += 96;
        float dBu = dl * uv;
        float Bv[16] = {B0.x,B0.y,B0.z,B0.w, B1.x,B1.y,B1.z,B1.w,
                        B2.x,B2.y,B2.z,B2.w, B3.x,B3.y,B3.z,B3.w};
        float Cv[16] = {C0.x,C0.y,C0.z,C0.w, C1.x,C1.y,C1.z,C1.w,
                        C2.x,C2.y,C2.z,C2.w, C3.x,C3.y,C3.z,C3.w};
        float y = uv * Dv;
        #pragma unroll
        for (int n = 0; n < 16; ++n) {
            h[n] = __expf(dl * Ac[n]) * h[n] + dBu * Bv[n];
            y += h[n] * Cv[n];
        }
        *yp = f2bf(y);
        yp += DINNER;
    }
}

// ---------------- host-side orchestration ----------------
extern "C" void kernel_launch(void* const* d_in, const int* in_sizes, int n_in,
                              void* d_out, int out_size, void* d_ws, size_t ws_size,
                              hipStream_t stream) {
    const float* x         = (const float*)d_in[0];
    const float* ln1_g     = (const float*)d_in[1];
    const float* ln1_b     = (const float*)d_in[2];
    const float* in_proj_w = (const float*)d_in[3];
    const float* conv_x_w  = (const float*)d_in[4];
    const float* conv_x_b  = (const float*)d_in[5];
    const float* conv_z_w  = (const float*)d_in[6];
    const float* conv_z_b  = (const float*)d_in[7];
    const float* x_proj_w  = (const float*)d_in[8];
    const float* dt_proj_w = (const float*)d_in[9];
    const float* dt_proj_b = (const float*)d_in[10];
    const float* A_log     = (const float*)d_in[11];
    const float* Dp        = (const float*)d_in[12];
    const float* out_proj_w= (const float*)d_in[13];
    const float* ln2_g     = (const float*)d_in[14];
    const float* ln2_b     = (const float*)d_in[15];
    const float* mlp_w1    = (const float*)d_in[16];
    const float* mlp_b1    = (const float*)d_in[17];
    const float* mlp_w2    = (const float*)d_in[18];
    const float* mlp_b2    = (const float*)d_in[19];
    float* out = (float*)d_out;

    char* p = (char*)d_ws;
    auto alloc = [&](size_t bytes) {
        char* r = p; p += (bytes + 255) & ~(size_t)255; return r;
    };
    u16*   w_in   = (u16*)  alloc((size_t)DINNER * DIMD * 2);
    u16*   w_xp   = (u16*)  alloc((size_t)96 * HALF * 2);
    u16*   w_dt   = (u16*)  alloc((size_t)HALF * DTRANK * 2);
    u16*   w_out  = (u16*)  alloc((size_t)DIMD * DINNER * 2);
    u16*   w_m1   = (u16*)  alloc((size_t)MLPD * DIMD * 2);
    u16*   w_m2   = (u16*)  alloc((size_t)DIMD * MLPD * 2);
    u16*   xn_bf  = (u16*)  alloc((size_t)NTOK * DIMD * 2);
    u16*   xz_bf  = (u16*)  alloc((size_t)NTOK * DINNER * 2);
    u16*   u_bf   = (u16*)  alloc((size_t)NTOK * HALF * 2);
    u16*   ycat   = (u16*)  alloc((size_t)NTOK * DINNER * 2);
    float* x_dbl  = (float*)alloc((size_t)NTOK * 96 * 4);
    u16*   xdbl_bf= (u16*)  alloc((size_t)NTOK * 96 * 2);
    float* delta  = (float*)alloc((size_t)NTOK * HALF * 4);
    float* x2     = (float*)alloc((size_t)NTOK * DIMD * 4);
    u16*   ln2_bf = (u16*)  alloc((size_t)NTOK * DIMD * 2);
    u16*   mlp_h  = (u16*)  alloc((size_t)NTOK * MLPD * 2);    // 32 MB
    // scan scratch aliases mlp_h (dead until mlp1):
    float* hfin = (float*)mlp_h;
    float* hin  = hfin + (size_t)BSZ * NCH * HALF * DSTATE;
    float* dsum = hin  + (size_t)BSZ * NCH * HALF * DSTATE;

    // fused LN1 + residual init (x2 = x) + weight conversions
    cvtln_kernel<<<NTOK + CVT_BLOCKS, 256, 0, stream>>>(
        x, ln1_g, ln1_b, xn_bf, x2,
        in_proj_w, w_in, x_proj_w, w_xp, dt_proj_w, w_dt,
        out_proj_w, w_out, mlp_w1, w_m1, mlp_w2, w_m2);

    // in_proj: xz_bf[4096,2048] = xn @ W^T (bf16 out, 2-phase 128x128)
    gemm128_kernel<5,128,1><<<dim3(NTOK/128, DINNER/128), 256, 0, stream>>>(
        xn_bf, DIMD, w_in, DIMD, DINNER, nullptr, nullptr,
        nullptr, nullptr, nullptr, nullptr, xz_bf);

    // depthwise conv + silu
    conv_silu_kernel<<<dim3(HALF/256, NTOK/8), 256, 0, stream>>>(
        xz_bf, conv_x_w, conv_x_b, conv_z_w, conv_z_b, u_bf, ycat);

    // x_proj
    gemm_small_kernel<<<dim3(NTOK/32, 96/16), 256, 0, stream>>>(
        u_bf, HALF, w_xp, HALF, 96, x_dbl, xdbl_bf);

    // dt_proj: delta = softplus(dt @ W^T + b)
    gemm128_kernel<1,64,1><<<dim3(NTOK/128, HALF/64), 256, 0, stream>>>(
        xdbl_bf, 96, w_dt, DTRANK, HALF, dt_proj_b, nullptr,
        delta, nullptr, nullptr, nullptr, nullptr);

    // chunk-parallel scan
    scan_p1_kernel<<<(BSZ*NCH*HALF)/256, 256, 0, stream>>>(
        delta, u_bf, x_dbl, A_log, hfin, dsum);
    scan_p2_kernel<<<(BSZ*HALF*DSTATE)/256, 256, 0, stream>>>(
        A_log, dsum, hfin, hin);
    scan_p3_kernel<<<(BSZ*NCH*HALF)/256, 256, 0, stream>>>(
        delta, u_bf, x_dbl, A_log, Dp, hin, ycat);

    // out_proj: 8-phase 256^2, split-K=4 atomically accumulated into x2
    // (x2 pre-initialized to x) -> x2 = x + mixer
    gemm256_kernel<6,4><<<dim3(NTOK/256, DIMD/256, 4), 512, 0, stream>>>(
        ycat, DINNER, w_out, DINNER, DIMD, nullptr,
        x2, nullptr, nullptr, nullptr, nullptr);

    // slim LN2: ln2_bf = LN(x2) ; out = x2 + mlp_b2 (MLP2 adds into it)
    ln_kernel<<<NTOK, 256, 0, stream>>>(
        x2, ln2_g, ln2_b, mlp_b2, ln2_bf, out);

    // MLP1: 8-phase 256^2: gelu(ln2 @ W1^T + b1) -> bf16
    gemm256_kernel<2,1><<<dim3(NTOK/256, MLPD/256, 1), 512, 0, stream>>>(
        ln2_bf, DIMD, w_m1, DIMD, MLPD, mlp_b1,
        nullptr, nullptr, nullptr, nullptr, mlp_h);

    // MLP2: 8-phase 256^2, split-K=4 atomically accumulated into out
    // -> out = x2 + b2 + mlp2
    gemm256_kernel<6,4><<<dim3(NTOK/256, DIMD/256, 4), 512, 0, stream>>>(
        mlp_h, MLPD, w_m2, MLPD, DIMD, nullptr,
        out, nullptr, nullptr, nullptr, nullptr);
}

// Round 9
// 423.182 us; speedup vs baseline: 1.8436x; 1.8436x over previous
//
#include <hip/hip_runtime.h>
#include <math.h>

#define DIMD    1024
#define MLPD    4096
#define DSTATE  16
#define DCONV   4
#define HALF    1024
#define DINNER  2048
#define DTRANK  64
#define BSZ     2
#define SEQ     2048
#define NTOK    (BSZ*SEQ)   // 4096
#define NCH     64
#define CL      (SEQ/NCH)   // 32

typedef short bf16x8 __attribute__((ext_vector_type(8)));
typedef float f32x4  __attribute__((ext_vector_type(4)));
typedef float f32x16 __attribute__((ext_vector_type(16)));
typedef unsigned short u16;
typedef unsigned int   u32;
typedef unsigned short u16x4 __attribute__((ext_vector_type(4)));

__device__ __forceinline__ u16 f2bf(float x) {
    union { float f; unsigned int u; } v; v.f = x;
    unsigned int r = (v.u + 0x7FFFu + ((v.u >> 16) & 1u)) >> 16;
    return (u16)r;
}
__device__ __forceinline__ float bf2f(u16 x) {
    union { unsigned int u; float f; } v; v.u = ((unsigned int)x) << 16;
    return v.f;
}

// ---------------- fused LN1 + weight f32->bf16 convert -------------------
#define SZ_WIN  (DINNER*DIMD)
#define SZ_WXP  (96*HALF)
#define SZ_WDT  (HALF*DTRANK)
#define SZ_WOUT (DIMD*DINNER)
#define SZ_WM1  (MLPD*DIMD)
#define SZ_WM2  (DIMD*MLPD)
#define SZ_TOT  (SZ_WIN+SZ_WXP+SZ_WDT+SZ_WOUT+SZ_WM1+SZ_WM2)
#define CVT_BLOCKS (SZ_TOT / 1024)

__global__ __launch_bounds__(256) void cvtln_kernel(
        const float* __restrict__ x, const float* __restrict__ g,
        const float* __restrict__ b, u16* __restrict__ xn_bf,
        const float* __restrict__ s0, u16* __restrict__ d0,
        const float* __restrict__ s1, u16* __restrict__ d1,
        const float* __restrict__ s2, u16* __restrict__ d2,
        const float* __restrict__ s3, u16* __restrict__ d3,
        const float* __restrict__ s4, u16* __restrict__ d4,
        const float* __restrict__ s5, u16* __restrict__ d5) {
    if (blockIdx.x >= NTOK) {
        int i = (blockIdx.x - NTOK) * 1024 + threadIdx.x * 4;
        #define CVT4(s, d) { \
            float4 v = *(const float4*)((s) + i); \
            u16x4 o; o[0]=f2bf(v.x); o[1]=f2bf(v.y); o[2]=f2bf(v.z); o[3]=f2bf(v.w); \
            *(u16x4*)((d) + i) = o; }
        if (i < SZ_WIN)  { CVT4(s0, d0); return; }  i -= SZ_WIN;
        if (i < SZ_WXP)  { CVT4(s1, d1); return; }  i -= SZ_WXP;
        if (i < SZ_WDT)  { CVT4(s2, d2); return; }  i -= SZ_WDT;
        if (i < SZ_WOUT) { CVT4(s3, d3); return; }  i -= SZ_WOUT;
        if (i < SZ_WM1)  { CVT4(s4, d4); return; }  i -= SZ_WM1;
        if (i < SZ_WM2)  { CVT4(s5, d5); }
        #undef CVT4
        return;
    }
    __shared__ float sm[4];
    int row = blockIdx.x;
    int t = threadIdx.x;
    const float4* xr = (const float4*)(x + (size_t)row * DIMD);
    float4 v = xr[t];
    float s = v.x + v.y + v.z + v.w;
    for (int off = 32; off > 0; off >>= 1) s += __shfl_down(s, off, 64);
    if ((t & 63) == 0) sm[t >> 6] = s;
    __syncthreads();
    float mu = (sm[0] + sm[1] + sm[2] + sm[3]) * (1.0f / DIMD);
    float dx = v.x - mu, dy = v.y - mu, dz = v.z - mu, dw = v.w - mu;
    float ss = dx*dx + dy*dy + dz*dz + dw*dw;
    for (int off = 32; off > 0; off >>= 1) ss += __shfl_down(ss, off, 64);
    __syncthreads();
    if ((t & 63) == 0) sm[t >> 6] = ss;
    __syncthreads();
    float var = (sm[0] + sm[1] + sm[2] + sm[3]) * (1.0f / DIMD);
    float rs = rsqrtf(var + 1e-5f);
    float4 gv = ((const float4*)g)[t];
    float4 bv = ((const float4*)b)[t];
    u16* o = xn_bf + (size_t)row * DIMD + t * 4;
    o[0] = f2bf(dx * rs * gv.x + bv.x);
    o[1] = f2bf(dy * rs * gv.y + bv.y);
    o[2] = f2bf(dz * rs * gv.z + bv.z);
    o[3] = f2bf(dw * rs * gv.w + bv.w);
}

// ---------------- x_proj GEMM: 4 waves = 2 m-tiles x 2 K-halves ----------
__global__ __launch_bounds__(256) void gemm_small_kernel(
        const u16* __restrict__ A, int lda,
        const u16* __restrict__ W, int K, int N,
        float* __restrict__ Cf, u16* __restrict__ Cb) {
    __shared__ f32x4 red[2][64];
    int t = threadIdx.x;
    int w = t >> 6, lane = t & 63;
    int mt = w & 1, kh = w >> 1;
    int m0 = blockIdx.x * 32 + mt * 16;
    int n0 = blockIdx.y * 16;
    int r = lane & 15, quad = lane >> 4;
    int Kh = K >> 1;
    f32x4 acc = {0.f, 0.f, 0.f, 0.f};
    const u16* ap = A + (size_t)(m0 + r) * lda + kh * Kh + quad * 8;
    const u16* wp = W + (size_t)(n0 + r) * K   + kh * Kh + quad * 8;
    for (int k = 0; k < Kh; k += 32) {
        bf16x8 av = *(const bf16x8*)(ap + k);
        bf16x8 bv = *(const bf16x8*)(wp + k);
        acc = __builtin_amdgcn_mfma_f32_16x16x32_bf16(av, bv, acc, 0, 0, 0);
    }
    if (kh == 1) red[mt][lane] = acc;
    __syncthreads();
    if (kh == 0) {
        f32x4 o = red[mt][lane];
        int col = n0 + r;
        #pragma unroll
        for (int i = 0; i < 4; ++i) {
            int row = m0 + quad * 4 + i;
            size_t idx = (size_t)row * N + col;
            float v = acc[i] + o[i];
            Cf[idx] = v;
            Cb[idx] = f2bf(v);
        }
    }
}

// ---------------- 2-phase 128xTN GEMM (in_proj / dt_proj) ----------------
// EPI: 1 bias+softplus f32 | 5 plain bf16
template<int EPI, int TN, int KS>
__global__ __launch_bounds__(256) void gemm128_kernel(
        const u16* __restrict__ A, int lda, const u16* __restrict__ W,
        int K, int N,
        const float* __restrict__ bias, const float* __restrict__ resid,
        float* __restrict__ Cf, float* __restrict__ Cf2,
        float* __restrict__ Cf3, float* __restrict__ Cf4,
        u16* __restrict__ Cb) {
    constexpr int NF = TN / 32;
    constexpr int NN = TN / 64;
    __shared__ u16 As0[128 * 32], As1[128 * 32];
    __shared__ u16 Bs0[TN * 32],  Bs1[TN * 32];
    const int t = threadIdx.x;
    const int w = t >> 6;
    const int lane = t & 63;
    const int r32 = lane & 31;
    const int kh  = lane >> 5;
    const int wm = w & 1, wn = w >> 1;
    const int m0 = blockIdx.x * 128;
    const int n0 = blockIdx.y * TN;
    const int Kloc = K / KS;
    const int kz = (KS > 1) ? blockIdx.z : 0;

    f32x16 acc[2][NN];
    #pragma unroll
    for (int mi = 0; mi < 2; ++mi)
        #pragma unroll
        for (int ni = 0; ni < NN; ++ni)
            acc[mi][ni] = (f32x16){0.f,0.f,0.f,0.f,0.f,0.f,0.f,0.f,
                                   0.f,0.f,0.f,0.f,0.f,0.f,0.f,0.f};

    const u16* pa[2];
    const u16* pb[NF / 2];
    #pragma unroll
    for (int i = 0; i < 2; ++i) {
        int c = (i * 4 + w) * 64 + lane;
        int row = c >> 2;
        int q = (c & 3) ^ ((row >> 1) & 3);
        pa[i] = A + (size_t)(m0 + row) * lda + (size_t)kz * Kloc + q * 8;
    }
    #pragma unroll
    for (int i = 0; i < NF / 2; ++i) {
        int c = (i * 4 + w) * 64 + lane;
        int row = c >> 2;
        int q = (c & 3) ^ ((row >> 1) & 3);
        pb[i] = W + (size_t)(n0 + row) * K + (size_t)kz * Kloc + q * 8;
    }
    const int gsw = (r32 >> 1) & 3;
    int aoff[2][2], boff[NN][2];
    #pragma unroll
    for (int mi = 0; mi < 2; ++mi)
        #pragma unroll
        for (int tt = 0; tt < 2; ++tt)
            aoff[mi][tt] = (wm * 64 + mi * 32 + r32) * 32 +
                           ((tt * 2 + kh) ^ gsw) * 8;
    #pragma unroll
    for (int ni = 0; ni < NN; ++ni)
        #pragma unroll
        for (int tt = 0; tt < 2; ++tt)
            boff[ni][tt] = (wn * (TN / 2) + ni * 32 + r32) * 32 +
                           ((tt * 2 + kh) ^ gsw) * 8;

    auto stage = [&](u16* __restrict__ Ad, u16* __restrict__ Bd) {
        #pragma unroll
        for (int i = 0; i < 2; ++i) {
            __builtin_amdgcn_global_load_lds(
                (const __attribute__((address_space(1))) u32*)pa[i],
                (__attribute__((address_space(3))) u32*)(Ad + (i * 4 + w) * 512),
                16, 0, 0);
            pa[i] += 32;
        }
        #pragma unroll
        for (int i = 0; i < NF / 2; ++i) {
            __builtin_amdgcn_global_load_lds(
                (const __attribute__((address_space(1))) u32*)pb[i],
                (__attribute__((address_space(3))) u32*)(Bd + (i * 4 + w) * 512),
                16, 0, 0);
            pb[i] += 32;
        }
    };
    auto compute = [&](const u16* __restrict__ Ab, const u16* __restrict__ Bb) {
        bf16x8 af[2][2], bfr[NN][2];
        #pragma unroll
        for (int mi = 0; mi < 2; ++mi)
            #pragma unroll
            for (int tt = 0; tt < 2; ++tt)
                af[mi][tt] = *(const bf16x8*)(Ab + aoff[mi][tt]);
        #pragma unroll
        for (int ni = 0; ni < NN; ++ni)
            #pragma unroll
            for (int tt = 0; tt < 2; ++tt)
                bfr[ni][tt] = *(const bf16x8*)(Bb + boff[ni][tt]);
        #pragma unroll
        for (int tt = 0; tt < 2; ++tt)
            #pragma unroll
            for (int mi = 0; mi < 2; ++mi)
                #pragma unroll
                for (int ni = 0; ni < NN; ++ni)
                    acc[mi][ni] = __builtin_amdgcn_mfma_f32_32x32x16_bf16(
                        af[mi][tt], bfr[ni][tt], acc[mi][ni], 0, 0, 0);
    };

    stage(As0, Bs0);
    for (int k0 = 0; k0 < Kloc; k0 += 64) {
        __syncthreads();
        if (k0 + 32 < Kloc) stage(As1, Bs1);
        compute(As0, Bs0);
        __syncthreads();
        if (k0 + 64 < Kloc) stage(As0, Bs0);
        compute(As1, Bs1);
    }

    float* Cfo = Cf;
    if (KS == 2 && kz == 1) Cfo = Cf2;
    if (KS == 4) Cfo = (kz == 0) ? Cf : (kz == 1) ? Cf2 : (kz == 2) ? Cf3 : Cf4;
    #pragma unroll
    for (int mi = 0; mi < 2; ++mi) {
        #pragma unroll
        for (int ni = 0; ni < NN; ++ni) {
            #pragma unroll
            for (int reg = 0; reg < 16; ++reg) {
                int row = m0 + wm * 64 + mi * 32 + (reg & 3) + 8 * (reg >> 2) + 4 * kh;
                int col = n0 + wn * (TN / 2) + ni * 32 + r32;
                size_t idx = (size_t)row * N + col;
                float v = acc[mi][ni][reg];
                if (EPI == 1) { v += bias[col]; v = (v > 20.f) ? v : log1pf(expf(v)); }
                if (EPI == 2) {
                    v += bias[col];
                    float e = __expf(fminf(1.5957691216f * v + 0.0713548162f * v * v * v, 80.f));
                    v = v * __fdividef(e, e + 1.f);
                }
                if (EPI == 3) { v += resid[idx]; }
                if (EPI == 4) { v += bias[col] + resid[idx]; }
                if (EPI == 2 || EPI == 5) Cb[idx] = f2bf(v);
                else                      Cfo[idx] = v;
            }
        }
    }
}

// ---------------- 8-wave 256x256 GEMM, half-tile pipelined ---------------
// 512 threads = 8 waves (2M x 4N). LDS: 4 half-buffers of K=32 each
// (4 x (16KB A + 16KB B) = 128 KB). Pipeline: while computing half s
// (2 phases), stage half s+3 -> issue-to-deadline gap = 4-5 phases.
// Counted vmcnt(8) once per half (drains half s+1), tail 4 -> 0.
// Granule XOR-swizzle: position p of row rr holds global granule
// p^(rr&3); read at q^(r&3) (2-way bank alias = free).
// EPI: 0 f32 partial (split-K via Cf..Cf4) | 2 bias+gelu -> bf16
template<int EPI, int KS_>
__global__ __launch_bounds__(512) void gemm256_kernel(
        const u16* __restrict__ A, int lda, const u16* __restrict__ W,
        int K, int N,
        const float* __restrict__ bias,
        float* __restrict__ Cf, float* __restrict__ Cf2,
        float* __restrict__ Cf3, float* __restrict__ Cf4,
        u16* __restrict__ Cb) {
    __shared__ u16 AH[4][256 * 32];
    __shared__ u16 BH[4][256 * 32];
    const int t = threadIdx.x;
    const int lane = t & 63;
    const int w = t >> 6;
    const int r = lane & 15, q = lane >> 4;
    const int wm = w >> 2, wn = w & 3;           // 2 x 4 wave grid
    const int m0 = blockIdx.x * 256;
    const int n0 = blockIdx.y * 256;
    const int kz = (KS_ > 1) ? blockIdx.z : 0;
    const int Kloc = K / KS_;
    const int NH = Kloc / 32;                    // half-tiles (>=3 required)

    f32x4 acc[8][4];
    #pragma unroll
    for (int mi = 0; mi < 8; ++mi)
        #pragma unroll
        for (int ni = 0; ni < 4; ++ni)
            acc[mi][ni] = (f32x4){0.f, 0.f, 0.f, 0.f};

    // read bases: elem = row*32 + (q^(r&3))*8 ; row&3 == r&3 for all frags
    const int gsw  = (q ^ (r & 3)) * 8;
    const int abase = (wm * 128 + r) * 32 + gsw;
    const int bbase = (wn * 64  + r) * 32 + gsw;
    // staging: call j covers rows [j*128, j*128+128); thread t -> row
    // j*128+(t>>2); dest linear elem = j*4096 + t*8 (HW appends lane*16B);
    // global source granule pre-swizzled by (t>>2)&3 = row&3.
    const int srow = t >> 2;
    const int scol = (((t & 3) ^ ((t >> 2) & 3)) * 8);
    const int sdst = w * 512;
    const size_t kzoff = (size_t)kz * Kloc;

    auto stA = [&](int buf, int s, int j) {
        const u16* src = A + (size_t)(m0 + j * 128 + srow) * lda + kzoff + s * 32 + scol;
        __builtin_amdgcn_global_load_lds(
            (const __attribute__((address_space(1))) u32*)src,
            (__attribute__((address_space(3))) u32*)(&AH[buf][j * 4096 + sdst]),
            16, 0, 0);
    };
    auto stB = [&](int buf, int s, int j) {
        const u16* src = W + (size_t)(n0 + j * 128 + srow) * (size_t)K + kzoff + s * 32 + scol;
        __builtin_amdgcn_global_load_lds(
            (const __attribute__((address_space(1))) u32*)src,
            (__attribute__((address_space(3))) u32*)(&BH[buf][j * 4096 + sdst]),
            16, 0, 0);
    };

    bf16x8 bfr[4];

    // Phase: ds_read frags -> stage 2 calls -> [vmcnt] -> barrier ->
    // lgkmcnt(0) -> sched_barrier -> setprio(1) 16xMFMA setprio(0) -> barrier
    #define PH(BUF, MH, STMT, VMODE)                                              \
    do {                                                                          \
        if (MH == 0) {                                                            \
            _Pragma("unroll")                                                     \
            for (int ni = 0; ni < 4; ++ni)                                        \
                bfr[ni] = *(const bf16x8*)(&BH[BUF][bbase + ni * 512]);           \
        }                                                                         \
        bf16x8 af0 = *(const bf16x8*)(&AH[BUF][abase + (MH*4+0)*512]);            \
        bf16x8 af1 = *(const bf16x8*)(&AH[BUF][abase + (MH*4+1)*512]);            \
        bf16x8 af2 = *(const bf16x8*)(&AH[BUF][abase + (MH*4+2)*512]);            \
        bf16x8 af3 = *(const bf16x8*)(&AH[BUF][abase + (MH*4+3)*512]);            \
        STMT;                                                                     \
        VMODE;                                                                    \
        __builtin_amdgcn_s_barrier();                                             \
        asm volatile("s_waitcnt lgkmcnt(0)" ::: "memory");                        \
        __builtin_amdgcn_sched_barrier(0);                                        \
        __builtin_amdgcn_s_setprio(1);                                            \
        _Pragma("unroll")                                                         \
        for (int ni = 0; ni < 4; ++ni) {                                          \
            acc[MH*4+0][ni] = __builtin_amdgcn_mfma_f32_16x16x32_bf16(af0, bfr[ni], acc[MH*4+0][ni], 0, 0, 0); \
            acc[MH*4+1][ni] = __builtin_amdgcn_mfma_f32_16x16x32_bf16(af1, bfr[ni], acc[MH*4+1][ni], 0, 0, 0); \
            acc[MH*4+2][ni] = __builtin_amdgcn_mfma_f32_16x16x32_bf16(af2, bfr[ni], acc[MH*4+2][ni], 0, 0, 0); \
            acc[MH*4+3][ni] = __builtin_amdgcn_mfma_f32_16x16x32_bf16(af3, bfr[ni], acc[MH*4+3][ni], 0, 0, 0); \
        }                                                                         \
        __builtin_amdgcn_s_setprio(0);                                            \
        __builtin_amdgcn_s_barrier();                                             \
    } while (0)

    #define VM_NONE do {} while (0)
    // end-of-pair wait: drain through half s+1 (4 loads/half/wave).
    #define VM_TAIL do {                                                          \
        if (st)               asm volatile("s_waitcnt vmcnt(8)" ::: "memory");    \
        else if (s + 2 < NH)  asm volatile("s_waitcnt vmcnt(4)" ::: "memory");    \
        else if (s + 1 < NH)  asm volatile("s_waitcnt vmcnt(0)" ::: "memory");    \
    } while (0)

    // prologue: stage halves 0,1,2 (12 loads/wave); drain half 0 (leave 8)
    #pragma unroll
    for (int h = 0; h < 3; ++h) {
        stA(h, h, 0); stA(h, h, 1);
        stB(h, h, 0); stB(h, h, 1);
    }
    asm volatile("s_waitcnt vmcnt(8)" ::: "memory");
    __builtin_amdgcn_s_barrier();

    for (int s = 0; s < NH; ++s) {
        const int  b  = s & 3;
        const int  s3 = s + 3;
        const int  b3 = s3 & 3;
        const bool st = s3 < NH;
        PH(b, 0, { if (st) { stA(b3, s3, 0); stA(b3, s3, 1); } }, VM_NONE);
        PH(b, 1, { if (st) { stB(b3, s3, 0); stB(b3, s3, 1); } }, VM_TAIL);
    }
    #undef PH
    #undef VM_NONE
    #undef VM_TAIL

    // ---- coalesced epilogue via per-wave LDS transpose ----
    float* wsc = ((float*)&AH[0][0]) + (size_t)w * (16 * 68);
    const int erow = lane >> 3;          // 0..7
    const int ecol = (lane & 7) * 4;     // 0,4,..,28
    float* Cfo = Cf;
    if (KS_ == 4)
        Cfo = (kz == 0) ? Cf : (kz == 1) ? Cf2 : (kz == 2) ? Cf3 : Cf4;
    #pragma unroll
    for (int mi = 0; mi < 8; ++mi) {
        #pragma unroll
        for (int ni = 0; ni < 4; ++ni)
            #pragma unroll
            for (int i = 0; i < 4; ++i)
                wsc[(q * 4 + i) * 68 + ni * 16 + r] = acc[mi][ni][i];
        asm volatile("s_waitcnt lgkmcnt(0)" ::: "memory");
        __builtin_amdgcn_sched_barrier(0);
        #pragma unroll
        for (int half = 0; half < 2; ++half) {
            #pragma unroll
            for (int k2 = 0; k2 < 2; ++k2) {
                int lr = half * 8 + erow;
                f32x4 v4 = *(const f32x4*)&wsc[lr * 68 + ecol + k2 * 32];
                int row = m0 + wm * 128 + mi * 16 + lr;
                int colb = n0 + wn * 64 + ecol + k2 * 32;
                size_t idx = (size_t)row * N + colb;
                if (EPI == 2) {
                    float4 bb = *(const float4*)&bias[colb];
                    float vv0 = v4[0] + bb.x, vv1 = v4[1] + bb.y;
                    float vv2 = v4[2] + bb.z, vv3 = v4[3] + bb.w;
                    u16x4 o;
                    #define GELU1(vx, slot) { \
                        float e = __expf(fminf(1.5957691216f * (vx) + 0.0713548162f * (vx)*(vx)*(vx), 80.f)); \
                        o[slot] = f2bf((vx) * __fdividef(e, e + 1.f)); }
                    GELU1(vv0, 0); GELU1(vv1, 1); GELU1(vv2, 2); GELU1(vv3, 3);
                    #undef GELU1
                    *(u16x4*)&Cb[idx] = o;
                } else {
                    *(f32x4*)&Cfo[idx] = v4;
                }
            }
        }
        asm volatile("s_waitcnt lgkmcnt(0)" ::: "memory");
        __builtin_amdgcn_sched_barrier(0);
    }
}

// ---------------- split-K=4 reduce: out = ΣP + bias + resid --------------
__global__ __launch_bounds__(256) void reduce4_kernel(
        const float* __restrict__ P0, const float* __restrict__ P1,
        const float* __restrict__ P2, const float* __restrict__ P3,
        const float* __restrict__ bias, const float* __restrict__ resid,
        float* __restrict__ out) {
    size_t idx = ((size_t)blockIdx.x * 256 + threadIdx.x) * 4;
    float4 a = *(const float4*)(P0 + idx);
    float4 b = *(const float4*)(P1 + idx);
    float4 c = *(const float4*)(P2 + idx);
    float4 d = *(const float4*)(P3 + idx);
    float4 rr = *(const float4*)(resid + idx);
    int col = (int)(idx & (DIMD - 1));
    float4 bb = *(const float4*)(bias + col);
    float4 o;
    o.x = a.x + b.x + c.x + d.x + rr.x + bb.x;
    o.y = a.y + b.y + c.y + d.y + rr.y + bb.y;
    o.z = a.z + b.z + c.z + d.z + rr.z + bb.z;
    o.w = a.w + b.w + c.w + d.w + rr.w + bb.w;
    *(float4*)(out + idx) = o;
}

// ---------------- fused out_proj reduce(4) + residual + LN2 --------------
__global__ __launch_bounds__(256) void reduce_ln4_kernel(
        const float* __restrict__ P0, const float* __restrict__ P1,
        const float* __restrict__ P2, const float* __restrict__ P3,
        const float* __restrict__ resid,
        const float* __restrict__ g, const float* __restrict__ b,
        float* __restrict__ x2, u16* __restrict__ out_bf) {
    __shared__ float sm[4];
    int row = blockIdx.x;
    int t = threadIdx.x;
    size_t base = (size_t)row * DIMD + t * 4;
    float4 a  = *(const float4*)(P0 + base);
    float4 p  = *(const float4*)(P1 + base);
    float4 c  = *(const float4*)(P2 + base);
    float4 d  = *(const float4*)(P3 + base);
    float4 rr = *(const float4*)(resid + base);
    float4 v;
    v.x = a.x + p.x + c.x + d.x + rr.x;
    v.y = a.y + p.y + c.y + d.y + rr.y;
    v.z = a.z + p.z + c.z + d.z + rr.z;
    v.w = a.w + p.w + c.w + d.w + rr.w;
    *(float4*)(x2 + base) = v;
    float s = v.x + v.y + v.z + v.w;
    for (int off = 32; off > 0; off >>= 1) s += __shfl_down(s, off, 64);
    if ((t & 63) == 0) sm[t >> 6] = s;
    __syncthreads();
    float mu = (sm[0] + sm[1] + sm[2] + sm[3]) * (1.0f / DIMD);
    float dx = v.x - mu, dy = v.y - mu, dz = v.z - mu, dw = v.w - mu;
    float ss = dx*dx + dy*dy + dz*dz + dw*dw;
    for (int off = 32; off > 0; off >>= 1) ss += __shfl_down(ss, off, 64);
    __syncthreads();
    if ((t & 63) == 0) sm[t >> 6] = ss;
    __syncthreads();
    float var = (sm[0] + sm[1] + sm[2] + sm[3]) * (1.0f / DIMD);
    float rs = rsqrtf(var + 1e-5f);
    float4 gv = ((const float4*)g)[t];
    float4 bv = ((const float4*)b)[t];
    u16* o = out_bf + base;
    o[0] = f2bf(dx * rs * gv.x + bv.x);
    o[1] = f2bf(dy * rs * gv.y + bv.y);
    o[2] = f2bf(dz * rs * gv.z + bv.z);
    o[3] = f2bf(dw * rs * gv.w + bv.w);
}

// ---------------- depthwise conv + SiLU, sliding window (8 l / thread) ---
__global__ __launch_bounds__(256) void conv_silu_kernel(
        const u16* __restrict__ xz,
        const float* __restrict__ wx, const float* __restrict__ bx,
        const float* __restrict__ wz, const float* __restrict__ bz,
        u16* __restrict__ u_bf, u16* __restrict__ ycat) {
    int c  = blockIdx.x * 256 + threadIdx.x;   // 0..1023
    int gy = blockIdx.y;                       // 0..NTOK/8-1
    int b  = gy >> 8;
    int l0 = (gy & 255) * 8;
    const u16* base = xz + ((size_t)(b * SEQ + l0)) * DINNER;
    float wxr[4], wzr[4];
    #pragma unroll
    for (int k = 0; k < 4; ++k) { wxr[k] = wx[c * 4 + k]; wzr[k] = wz[c * 4 + k]; }
    float bxv = bx[c], bzv = bz[c];
    float xm1 = (l0 > 0) ? bf2f(base[c - DINNER]) : 0.f;
    float x0v = bf2f(base[c]);
    float x1v = bf2f(base[c + DINNER]);
    float zm1 = (l0 > 0) ? bf2f(base[HALF + c - DINNER]) : 0.f;
    float z0v = bf2f(base[HALF + c]);
    float z1v = bf2f(base[HALF + c + DINNER]);
    u16* up = u_bf + ((size_t)(b * SEQ + l0)) * HALF + c;
    u16* yp = ycat + ((size_t)(b * SEQ + l0)) * DINNER + HALF + c;
    #pragma unroll
    for (int l = 0; l < 8; ++l) {
        bool in = (l0 + l + 2) < SEQ;
        float x2v = in ? bf2f(base[(size_t)(l + 2) * DINNER + c]) : 0.f;
        float z2v = in ? bf2f(base[(size_t)(l + 2) * DINNER + HALF + c]) : 0.f;
        float ax = bxv + wxr[0]*xm1 + wxr[1]*x0v + wxr[2]*x1v + wxr[3]*x2v;
        float az = bzv + wzr[0]*zm1 + wzr[1]*z0v + wzr[2]*z1v + wzr[3]*z2v;
        float sx = ax * __fdividef(1.f, 1.f + __expf(-ax));
        float sz = az * __fdividef(1.f, 1.f + __expf(-az));
        *up = f2bf(sx); *yp = f2bf(sz);
        up += HALF; yp += DINNER;
        xm1 = x0v; x0v = x1v; x1v = x2v;
        zm1 = z0v; z0v = z1v; z1v = z2v;
    }
}

// ---------------- chunk-parallel selective scan (thread per chain) -------
__global__ __launch_bounds__(256) void scan_p1_kernel(
        const float* __restrict__ delta, const u16* __restrict__ u_bf,
        const float* __restrict__ x_dbl, const float* __restrict__ A_log,
        float* __restrict__ hfin, float* __restrict__ dsum) {
    int t  = blockIdx.x * 256 + threadIdx.x;
    int d  = t & (HALF - 1);
    int ch = (t >> 10) & (NCH - 1);
    int b  = t >> 16;
    float Ac[16], h[16];
    #pragma unroll
    for (int i = 0; i < 4; ++i) {
        float4 a = *(const float4*)&A_log[d * DSTATE + i * 4];
        Ac[4*i+0] = -__expf(a.x); Ac[4*i+1] = -__expf(a.y);
        Ac[4*i+2] = -__expf(a.z); Ac[4*i+3] = -__expf(a.w);
        h[4*i+0] = 0.f; h[4*i+1] = 0.f; h[4*i+2] = 0.f; h[4*i+3] = 0.f;
    }
    int l0 = b * SEQ + ch * CL;
    size_t off = (size_t)l0 * HALF + d;
    const float* xrow = x_dbl + (size_t)l0 * 96;
    float ds = 0.f;
    #pragma unroll 4
    for (int l = 0; l < CL; ++l) {
        float dl = delta[off];
        float uv = bf2f(u_bf[off]);
        off += HALF;
        float4 B0 = *(const float4*)(xrow + 64);
        float4 B1 = *(const float4*)(xrow + 68);
        float4 B2 = *(const float4*)(xrow + 72);
        float4 B3 = *(const float4*)(xrow + 76);
        xrow += 96;
        float dBu = dl * uv;
        ds += dl;
        float Bv[16] = {B0.x,B0.y,B0.z,B0.w, B1.x,B1.y,B1.z,B1.w,
                        B2.x,B2.y,B2.z,B2.w, B3.x,B3.y,B3.z,B3.w};
        #pragma unroll
        for (int n = 0; n < 16; ++n)
            h[n] = __expf(dl * Ac[n]) * h[n] + dBu * Bv[n];
    }
    float4* hf = (float4*)&hfin[(size_t)t * 16];
    #pragma unroll
    for (int i = 0; i < 4; ++i)
        hf[i] = (float4){h[4*i+0], h[4*i+1], h[4*i+2], h[4*i+3]};
    dsum[t] = ds;
}

__global__ __launch_bounds__(256) void scan_p2_kernel(
        const float* __restrict__ A_log, const float* __restrict__ dsum,
        const float* __restrict__ hfin, float* __restrict__ hin) {
    int t = blockIdx.x * 256 + threadIdx.x;
    int n = t & 15;
    int d = (t >> 4) & (HALF - 1);
    int b = t >> 14;
    float Ac = -__expf(A_log[d * DSTATE + n]);
    float h = 0.f;
    for (int ch = 0; ch < NCH; ++ch) {
        size_t chain = ((size_t)(b * NCH + ch) * HALF) + d;
        hin[chain * 16 + n] = h;
        float ds = dsum[chain];
        h = __expf(Ac * ds) * h + hfin[chain * 16 + n];
    }
}

__global__ __launch_bounds__(256) void scan_p3_kernel(
        const float* __restrict__ delta, const u16* __restrict__ u_bf,
        const float* __restrict__ x_dbl, const float* __restrict__ A_log,
        const float* __restrict__ Dp, const float* __restrict__ hin,
        u16* __restrict__ ycat) {
    int t  = blockIdx.x * 256 + threadIdx.x;
    int d  = t & (HALF - 1);
    int ch = (t >> 10) & (NCH - 1);
    int b  = t >> 16;
    float Ac[16], h[16];
    #pragma unroll
    for (int i = 0; i < 4; ++i) {
        float4 a  = *(const float4*)&A_log[d * DSTATE + i * 4];
        float4 hv = *(const float4*)&hin[(size_t)t * 16 + i * 4];
        Ac[4*i+0] = -__expf(a.x); Ac[4*i+1] = -__expf(a.y);
        Ac[4*i+2] = -__expf(a.z); Ac[4*i+3] = -__expf(a.w);
        h[4*i+0] = hv.x; h[4*i+1] = hv.y; h[4*i+2] = hv.z; h[4*i+3] = hv.w;
    }
    float Dv = Dp[d];
    int l0 = b * SEQ + ch * CL;
    size_t off = (size_t)l0 * HALF + d;
    const float* xrow = x_dbl + (size_t)l0 * 96;
    u16* yp = ycat + (size_t)l0 * DINNER + d;
    #pragma unroll 4
    for (int l = 0; l < CL; ++l) {
        float dl = delta[off];
        float uv = bf2f(u_bf[off]);
        off += HALF;
        float4 B0 = *(const float4*)(xrow + 64);
        float4 B1 = *(const float4*)(xrow + 68);
        float4 B2 = *(const float4*)(xrow + 72);
        float4 B3 = *(const float4*)(xrow + 76);
        float4 C0 = *(const float4*)(xrow + 80);
        float4 C1 = *(const float4*)(xrow + 84);
        float4 C2 = *(const float4*)(xrow + 88);
        float4 C3 = *(const float4*)(xrow + 92);
        xrow += 96;
        float dBu = dl * uv;
        float Bv[16] = {B0.x,B0.y,B0.z,B0.w, B1.x,B1.y,B1.z,B1.w,
                        B2.x,B2.y,B2.z,B2.w, B3.x,B3.y,B3.z,B3.w};
        float Cv[16] = {C0.x,C0.y,C0.z,C0.w, C1.x,C1.y,C1.z,C1.w,
                        C2.x,C2.y,C2.z,C2.w, C3.x,C3.y,C3.z,C3.w};
        float y = uv * Dv;
        #pragma unroll
        for (int n = 0; n < 16; ++n) {
            h[n] = __expf(dl * Ac[n]) * h[n] + dBu * Bv[n];
            y += h[n] * Cv[n];
        }
        *yp = f2bf(y);
        yp += DINNER;
    }
}

// ---------------- host-side orchestration ----------------
extern "C" void kernel_launch(void* const* d_in, const int* in_sizes, int n_in,
                              void* d_out, int out_size, void* d_ws, size_t ws_size,
                              hipStream_t stream) {
    const float* x         = (const float*)d_in[0];
    const float* ln1_g     = (const float*)d_in[1];
    const float* ln1_b     = (const float*)d_in[2];
    const float* in_proj_w = (const float*)d_in[3];
    const float* conv_x_w  = (const float*)d_in[4];
    const float* conv_x_b  = (const float*)d_in[5];
    const float* conv_z_w  = (const float*)d_in[6];
    const float* conv_z_b  = (const float*)d_in[7];
    const float* x_proj_w  = (const float*)d_in[8];
    const float* dt_proj_w = (const float*)d_in[9];
    const float* dt_proj_b = (const float*)d_in[10];
    const float* A_log     = (const float*)d_in[11];
    const float* Dp        = (const float*)d_in[12];
    const float* out_proj_w= (const float*)d_in[13];
    const float* ln2_g     = (const float*)d_in[14];
    const float* ln2_b     = (const float*)d_in[15];
    const float* mlp_w1    = (const float*)d_in[16];
    const float* mlp_b1    = (const float*)d_in[17];
    const float* mlp_w2    = (const float*)d_in[18];
    const float* mlp_b2    = (const float*)d_in[19];
    float* out = (float*)d_out;

    char* p = (char*)d_ws;
    auto alloc = [&](size_t bytes) {
        char* r = p; p += (bytes + 255) & ~(size_t)255; return r;
    };
    const size_t MB16 = (size_t)16 * 1024 * 1024;
    u16*   w_in   = (u16*)  alloc((size_t)DINNER * DIMD * 2);
    u16*   w_xp   = (u16*)  alloc((size_t)96 * HALF * 2);
    u16*   w_dt   = (u16*)  alloc((size_t)HALF * DTRANK * 2);
    u16*   w_out  = (u16*)  alloc((size_t)DIMD * DINNER * 2);
    u16*   w_m1   = (u16*)  alloc((size_t)MLPD * DIMD * 2);
    u16*   w_m2   = (u16*)  alloc((size_t)DIMD * MLPD * 2);
    // 64 MB partial slab, sub-aliased by dead activation buffers:
    char*  Pb     =         alloc(4 * MB16);
    float* delta  = (float*)(Pb);                 // 16 MB
    u16*   xz_bf  = (u16*)  (Pb + 1 * MB16);      // 16 MB
    u16*   ycat   = (u16*)  (Pb + 2 * MB16);      // 16 MB
    u16*   u_bf   = (u16*)  (Pb + 3 * MB16);      //  8 MB
    u16*   xn_bf  = (u16*)  (Pb + 3 * MB16 + MB16 / 2); // 8 MB
    float* x_dbl  = (float*)alloc((size_t)NTOK * 96 * 4);
    u16*   xdbl_bf= (u16*)  alloc((size_t)NTOK * 96 * 2);
    float* x2     = (float*)alloc((size_t)NTOK * DIMD * 4);
    u16*   ln2_bf = (u16*)  alloc((size_t)NTOK * DIMD * 2);
    u16*   mlp_h  = (u16*)  alloc((size_t)NTOK * MLPD * 2);    // 32 MB
    // scan scratch aliases mlp_h (dead until mlp1):
    float* hfin = (float*)mlp_h;
    float* hin  = hfin + (size_t)BSZ * NCH * HALF * DSTATE;
    float* dsum = hin  + (size_t)BSZ * NCH * HALF * DSTATE;
    // out_proj split-K=4 partials: delta+xz slots (dead) + mlp_h (scan done)
    float* R0 = (float*)(Pb);
    float* R1 = (float*)(Pb + 1 * MB16);
    float* R2 = (float*)mlp_h;
    float* R3 = (float*)((char*)mlp_h + MB16);
    // MLP2 split-K=4 partials: whole slab (all activations dead by then)
    float* Q0 = (float*)(Pb);
    float* Q1 = (float*)(Pb + 1 * MB16);
    float* Q2 = (float*)(Pb + 2 * MB16);
    float* Q3 = (float*)(Pb + 3 * MB16);

    // fused LN1 + weight conversions
    cvtln_kernel<<<NTOK + CVT_BLOCKS, 256, 0, stream>>>(
        x, ln1_g, ln1_b, xn_bf,
        in_proj_w, w_in, x_proj_w, w_xp, dt_proj_w, w_dt,
        out_proj_w, w_out, mlp_w1, w_m1, mlp_w2, w_m2);

    // in_proj: xz_bf[4096,2048] = xn @ W^T (bf16 out, 2-phase 128x128)
    gemm128_kernel<5,128,1><<<dim3(NTOK/128, DINNER/128), 256, 0, stream>>>(
        xn_bf, DIMD, w_in, DIMD, DINNER, nullptr, nullptr,
        nullptr, nullptr, nullptr, nullptr, xz_bf);

    // depthwise conv + silu
    conv_silu_kernel<<<dim3(HALF/256, NTOK/8), 256, 0, stream>>>(
        xz_bf, conv_x_w, conv_x_b, conv_z_w, conv_z_b, u_bf, ycat);

    // x_proj
    gemm_small_kernel<<<dim3(NTOK/32, 96/16), 256, 0, stream>>>(
        u_bf, HALF, w_xp, HALF, 96, x_dbl, xdbl_bf);

    // dt_proj: delta = softplus(dt @ W^T + b)
    gemm128_kernel<1,64,1><<<dim3(NTOK/128, HALF/64), 256, 0, stream>>>(
        xdbl_bf, 96, w_dt, DTRANK, HALF, dt_proj_b, nullptr,
        delta, nullptr, nullptr, nullptr, nullptr);

    // chunk-parallel scan
    scan_p1_kernel<<<(BSZ*NCH*HALF)/256, 256, 0, stream>>>(
        delta, u_bf, x_dbl, A_log, hfin, dsum);
    scan_p2_kernel<<<(BSZ*HALF*DSTATE)/256, 256, 0, stream>>>(
        A_log, dsum, hfin, hin);
    scan_p3_kernel<<<(BSZ*NCH*HALF)/256, 256, 0, stream>>>(
        delta, u_bf, x_dbl, A_log, Dp, hin, ycat);

    // out_proj: half-tile-pipelined 256^2, split-K=4: P = ycat @ W^T
    gemm256_kernel<0,4><<<dim3(NTOK/256, DIMD/256, 4), 512, 0, stream>>>(
        ycat, DINNER, w_out, DINNER, DIMD, nullptr,
        R0, R1, R2, R3, nullptr);
    reduce_ln4_kernel<<<NTOK, 256, 0, stream>>>(
        R0, R1, R2, R3, x, ln2_g, ln2_b, x2, ln2_bf);

    // MLP1: half-tile-pipelined 256^2: gelu(ln2 @ W1^T + b1) -> bf16
    gemm256_kernel<2,1><<<dim3(NTOK/256, MLPD/256, 1), 512, 0, stream>>>(
        ln2_bf, DIMD, w_m1, DIMD, MLPD, mlp_b1,
        nullptr, nullptr, nullptr, nullptr, mlp_h);

    // MLP2: half-tile-pipelined 256^2, split-K=4: P = mlp_h @ W2^T
    gemm256_kernel<0,4><<<dim3(NTOK/256, DIMD/256, 4), 512, 0, stream>>>(
        mlp_h, MLPD, w_m2, MLPD, DIMD, nullptr,
        Q0, Q1, Q2, Q3, nullptr);
    reduce4_kernel<<<(NTOK*DIMD)/1024, 256, 0, stream>>>(
        Q0, Q1, Q2, Q3, mlp_b2, x2, out);
}

// Round 10
// 401.907 us; speedup vs baseline: 1.9412x; 1.0529x over previous
//
#include <hip/hip_runtime.h>
#include <math.h>

#define DIMD    1024
#define MLPD    4096
#define DSTATE  16
#define DCONV   4
#define HALF    1024
#define DINNER  2048
#define DTRANK  64
#define BSZ     2
#define SEQ     2048
#define NTOK    (BSZ*SEQ)   // 4096
#define NCH     64
#define CL      (SEQ/NCH)   // 32

typedef short bf16x8 __attribute__((ext_vector_type(8)));
typedef float f32x4  __attribute__((ext_vector_type(4)));
typedef float f32x16 __attribute__((ext_vector_type(16)));
typedef unsigned short u16;
typedef unsigned int   u32;
typedef unsigned short u16x4 __attribute__((ext_vector_type(4)));

__device__ __forceinline__ u16 f2bf(float x) {
    union { float f; unsigned int u; } v; v.f = x;
    unsigned int r = (v.u + 0x7FFFu + ((v.u >> 16) & 1u)) >> 16;
    return (u16)r;
}
__device__ __forceinline__ float bf2f(u16 x) {
    union { unsigned int u; float f; } v; v.u = ((unsigned int)x) << 16;
    return v.f;
}

// ---------------- fused LN1 + weight f32->bf16 convert -------------------
#define SZ_WIN  (DINNER*DIMD)
#define SZ_WXP  (96*HALF)
#define SZ_WDT  (HALF*DTRANK)
#define SZ_WOUT (DIMD*DINNER)
#define SZ_WM1  (MLPD*DIMD)
#define SZ_WM2  (DIMD*MLPD)
#define SZ_TOT  (SZ_WIN+SZ_WXP+SZ_WDT+SZ_WOUT+SZ_WM1+SZ_WM2)
#define CVT_BLOCKS (SZ_TOT / 1024)

__global__ __launch_bounds__(256) void cvtln_kernel(
        const float* __restrict__ x, const float* __restrict__ g,
        const float* __restrict__ b, u16* __restrict__ xn_bf,
        const float* __restrict__ s0, u16* __restrict__ d0,
        const float* __restrict__ s1, u16* __restrict__ d1,
        const float* __restrict__ s2, u16* __restrict__ d2,
        const float* __restrict__ s3, u16* __restrict__ d3,
        const float* __restrict__ s4, u16* __restrict__ d4,
        const float* __restrict__ s5, u16* __restrict__ d5) {
    if (blockIdx.x >= NTOK) {
        int i = (blockIdx.x - NTOK) * 1024 + threadIdx.x * 4;
        #define CVT4(s, d) { \
            float4 v = *(const float4*)((s) + i); \
            u16x4 o; o[0]=f2bf(v.x); o[1]=f2bf(v.y); o[2]=f2bf(v.z); o[3]=f2bf(v.w); \
            *(u16x4*)((d) + i) = o; }
        if (i < SZ_WIN)  { CVT4(s0, d0); return; }  i -= SZ_WIN;
        if (i < SZ_WXP)  { CVT4(s1, d1); return; }  i -= SZ_WXP;
        if (i < SZ_WDT)  { CVT4(s2, d2); return; }  i -= SZ_WDT;
        if (i < SZ_WOUT) { CVT4(s3, d3); return; }  i -= SZ_WOUT;
        if (i < SZ_WM1)  { CVT4(s4, d4); return; }  i -= SZ_WM1;
        if (i < SZ_WM2)  { CVT4(s5, d5); }
        #undef CVT4
        return;
    }
    __shared__ float sm[4];
    int row = blockIdx.x;
    int t = threadIdx.x;
    const float4* xr = (const float4*)(x + (size_t)row * DIMD);
    float4 v = xr[t];
    float s = v.x + v.y + v.z + v.w;
    for (int off = 32; off > 0; off >>= 1) s += __shfl_down(s, off, 64);
    if ((t & 63) == 0) sm[t >> 6] = s;
    __syncthreads();
    float mu = (sm[0] + sm[1] + sm[2] + sm[3]) * (1.0f / DIMD);
    float dx = v.x - mu, dy = v.y - mu, dz = v.z - mu, dw = v.w - mu;
    float ss = dx*dx + dy*dy + dz*dz + dw*dw;
    for (int off = 32; off > 0; off >>= 1) ss += __shfl_down(ss, off, 64);
    __syncthreads();
    if ((t & 63) == 0) sm[t >> 6] = ss;
    __syncthreads();
    float var = (sm[0] + sm[1] + sm[2] + sm[3]) * (1.0f / DIMD);
    float rs = rsqrtf(var + 1e-5f);
    float4 gv = ((const float4*)g)[t];
    float4 bv = ((const float4*)b)[t];
    u16* o = xn_bf + (size_t)row * DIMD + t * 4;
    o[0] = f2bf(dx * rs * gv.x + bv.x);
    o[1] = f2bf(dy * rs * gv.y + bv.y);
    o[2] = f2bf(dz * rs * gv.z + bv.z);
    o[3] = f2bf(dw * rs * gv.w + bv.w);
}

// ---------------- x_proj GEMM: 4 waves = 2 m-tiles x 2 K-halves ----------
__global__ __launch_bounds__(256) void gemm_small_kernel(
        const u16* __restrict__ A, int lda,
        const u16* __restrict__ W, int K, int N,
        float* __restrict__ Cf, u16* __restrict__ Cb) {
    __shared__ f32x4 red[2][64];
    int t = threadIdx.x;
    int w = t >> 6, lane = t & 63;
    int mt = w & 1, kh = w >> 1;
    int m0 = blockIdx.x * 32 + mt * 16;
    int n0 = blockIdx.y * 16;
    int r = lane & 15, quad = lane >> 4;
    int Kh = K >> 1;
    f32x4 acc = {0.f, 0.f, 0.f, 0.f};
    const u16* ap = A + (size_t)(m0 + r) * lda + kh * Kh + quad * 8;
    const u16* wp = W + (size_t)(n0 + r) * K   + kh * Kh + quad * 8;
    for (int k = 0; k < Kh; k += 32) {
        bf16x8 av = *(const bf16x8*)(ap + k);
        bf16x8 bv = *(const bf16x8*)(wp + k);
        acc = __builtin_amdgcn_mfma_f32_16x16x32_bf16(av, bv, acc, 0, 0, 0);
    }
    if (kh == 1) red[mt][lane] = acc;
    __syncthreads();
    if (kh == 0) {
        f32x4 o = red[mt][lane];
        int col = n0 + r;
        #pragma unroll
        for (int i = 0; i < 4; ++i) {
            int row = m0 + quad * 4 + i;
            size_t idx = (size_t)row * N + col;
            float v = acc[i] + o[i];
            Cf[idx] = v;
            Cb[idx] = f2bf(v);
        }
    }
}

// ---------------- 2-phase 128xTN GEMM ----------------
// EPI: 1 bias+softplus f32 | 3 +resid f32 | 4 bias+resid f32 | 5 plain bf16
template<int EPI, int TN, int KS>
__global__ __launch_bounds__(256) void gemm128_kernel(
        const u16* __restrict__ A, int lda, const u16* __restrict__ W,
        int K, int N,
        const float* __restrict__ bias, const float* __restrict__ resid,
        float* __restrict__ Cf, float* __restrict__ Cf2,
        float* __restrict__ Cf3, float* __restrict__ Cf4,
        u16* __restrict__ Cb) {
    constexpr int NF = TN / 32;
    constexpr int NN = TN / 64;
    __shared__ u16 As0[128 * 32], As1[128 * 32];
    __shared__ u16 Bs0[TN * 32],  Bs1[TN * 32];
    const int t = threadIdx.x;
    const int w = t >> 6;
    const int lane = t & 63;
    const int r32 = lane & 31;
    const int kh  = lane >> 5;
    const int wm = w & 1, wn = w >> 1;
    const int m0 = blockIdx.x * 128;
    const int n0 = blockIdx.y * TN;
    const int Kloc = K / KS;
    const int kz = (KS > 1) ? blockIdx.z : 0;

    f32x16 acc[2][NN];
    #pragma unroll
    for (int mi = 0; mi < 2; ++mi)
        #pragma unroll
        for (int ni = 0; ni < NN; ++ni)
            acc[mi][ni] = (f32x16){0.f,0.f,0.f,0.f,0.f,0.f,0.f,0.f,
                                   0.f,0.f,0.f,0.f,0.f,0.f,0.f,0.f};

    const u16* pa[2];
    const u16* pb[NF / 2];
    #pragma unroll
    for (int i = 0; i < 2; ++i) {
        int c = (i * 4 + w) * 64 + lane;
        int row = c >> 2;
        int q = (c & 3) ^ ((row >> 1) & 3);
        pa[i] = A + (size_t)(m0 + row) * lda + (size_t)kz * Kloc + q * 8;
    }
    #pragma unroll
    for (int i = 0; i < NF / 2; ++i) {
        int c = (i * 4 + w) * 64 + lane;
        int row = c >> 2;
        int q = (c & 3) ^ ((row >> 1) & 3);
        pb[i] = W + (size_t)(n0 + row) * K + (size_t)kz * Kloc + q * 8;
    }
    const int gsw = (r32 >> 1) & 3;
    int aoff[2][2], boff[NN][2];
    #pragma unroll
    for (int mi = 0; mi < 2; ++mi)
        #pragma unroll
        for (int tt = 0; tt < 2; ++tt)
            aoff[mi][tt] = (wm * 64 + mi * 32 + r32) * 32 +
                           ((tt * 2 + kh) ^ gsw) * 8;
    #pragma unroll
    for (int ni = 0; ni < NN; ++ni)
        #pragma unroll
        for (int tt = 0; tt < 2; ++tt)
            boff[ni][tt] = (wn * (TN / 2) + ni * 32 + r32) * 32 +
                           ((tt * 2 + kh) ^ gsw) * 8;

    auto stage = [&](u16* __restrict__ Ad, u16* __restrict__ Bd) {
        #pragma unroll
        for (int i = 0; i < 2; ++i) {
            __builtin_amdgcn_global_load_lds(
                (const __attribute__((address_space(1))) u32*)pa[i],
                (__attribute__((address_space(3))) u32*)(Ad + (i * 4 + w) * 512),
                16, 0, 0);
            pa[i] += 32;
        }
        #pragma unroll
        for (int i = 0; i < NF / 2; ++i) {
            __builtin_amdgcn_global_load_lds(
                (const __attribute__((address_space(1))) u32*)pb[i],
                (__attribute__((address_space(3))) u32*)(Bd + (i * 4 + w) * 512),
                16, 0, 0);
            pb[i] += 32;
        }
    };
    auto compute = [&](const u16* __restrict__ Ab, const u16* __restrict__ Bb) {
        bf16x8 af[2][2], bfr[NN][2];
        #pragma unroll
        for (int mi = 0; mi < 2; ++mi)
            #pragma unroll
            for (int tt = 0; tt < 2; ++tt)
                af[mi][tt] = *(const bf16x8*)(Ab + aoff[mi][tt]);
        #pragma unroll
        for (int ni = 0; ni < NN; ++ni)
            #pragma unroll
            for (int tt = 0; tt < 2; ++tt)
                bfr[ni][tt] = *(const bf16x8*)(Bb + boff[ni][tt]);
        #pragma unroll
        for (int tt = 0; tt < 2; ++tt)
            #pragma unroll
            for (int mi = 0; mi < 2; ++mi)
                #pragma unroll
                for (int ni = 0; ni < NN; ++ni)
                    acc[mi][ni] = __builtin_amdgcn_mfma_f32_32x32x16_bf16(
                        af[mi][tt], bfr[ni][tt], acc[mi][ni], 0, 0, 0);
    };

    stage(As0, Bs0);
    for (int k0 = 0; k0 < Kloc; k0 += 64) {
        __syncthreads();
        if (k0 + 32 < Kloc) stage(As1, Bs1);
        compute(As0, Bs0);
        __syncthreads();
        if (k0 + 64 < Kloc) stage(As0, Bs0);
        compute(As1, Bs1);
    }

    float* Cfo = Cf;
    if (KS == 2 && kz == 1) Cfo = Cf2;
    if (KS == 4) Cfo = (kz == 0) ? Cf : (kz == 1) ? Cf2 : (kz == 2) ? Cf3 : Cf4;
    #pragma unroll
    for (int mi = 0; mi < 2; ++mi) {
        #pragma unroll
        for (int ni = 0; ni < NN; ++ni) {
            #pragma unroll
            for (int reg = 0; reg < 16; ++reg) {
                int row = m0 + wm * 64 + mi * 32 + (reg & 3) + 8 * (reg >> 2) + 4 * kh;
                int col = n0 + wn * (TN / 2) + ni * 32 + r32;
                size_t idx = (size_t)row * N + col;
                float v = acc[mi][ni][reg];
                if (EPI == 1) { v += bias[col]; v = (v > 20.f) ? v : log1pf(expf(v)); }
                if (EPI == 2) {
                    v += bias[col];
                    float e = __expf(fminf(1.5957691216f * v + 0.0713548162f * v * v * v, 80.f));
                    v = v * __fdividef(e, e + 1.f);
                }
                if (EPI == 3) { v += resid[idx]; }
                if (EPI == 4) { v += bias[col] + resid[idx]; }
                if (EPI == 2 || EPI == 5) Cb[idx] = f2bf(v);
                else                      Cfo[idx] = v;
            }
        }
    }
}

// ---------------- 8-phase 256x256 GEMM (MLP1) ----------------------------
// Round-7 version: 512 threads = 8 waves (2M x 4N); BK=64; XOR-swizzled
// LDS double-buffer; counted vmcnt(2) at phases 3/7; coalesced epilogue.
// EPI: 0 f32 partial | 2 bias+gelu -> bf16
template<int EPI, int KS_>
__global__ __launch_bounds__(512) void gemm256_kernel(
        const u16* __restrict__ A, int lda, const u16* __restrict__ W,
        int K, int N,
        const float* __restrict__ bias,
        float* __restrict__ Cf, float* __restrict__ Cf2,
        float* __restrict__ Cf3, float* __restrict__ Cf4,
        u16* __restrict__ Cb) {
    __shared__ u16 As[2][256 * 64];   // [buf][row*64 + swizzled col]
    __shared__ u16 Bs[2][256 * 64];
    const int t = threadIdx.x;
    const int lane = t & 63;
    const int w = t >> 6;
    const int r = lane & 15, q = lane >> 4;
    const int wm = w >> 2, wn = w & 3;           // 2 x 4 wave grid
    const int m0 = blockIdx.x * 256;
    const int n0 = blockIdx.y * 256;
    const int kz = (KS_ > 1) ? blockIdx.z : 0;
    const int Kloc = K / KS_;
    const int NI = Kloc / 128;                   // iters (2 K-tiles of 64 each)

    f32x4 acc[8][4];
    #pragma unroll
    for (int mi = 0; mi < 8; ++mi)
        #pragma unroll
        for (int ni = 0; ni < 4; ++ni)
            acc[mi][ni] = (f32x4){0.f, 0.f, 0.f, 0.f};

    const int aoffb = (wm * 128 + r) * 64;
    const int boffb = (wn * 64  + r) * 64;
    const int kswz[2] = { ((0 + q) ^ (r & 7)) * 8,
                          ((4 + q) ^ (r & 7)) * 8 };
    const int srow = t >> 3;
    const int scol = (((t & 7) ^ (srow & 7)) * 8);
    const int sdst = (t >> 6) * 512;
    const size_t kzoff = (size_t)kz * Kloc;

    auto stA = [&](int buf, int T, int j) {
        const u16* src = A + (size_t)(m0 + j * 64 + srow) * lda + kzoff + T * 64 + scol;
        __builtin_amdgcn_global_load_lds(
            (const __attribute__((address_space(1))) u32*)src,
            (__attribute__((address_space(3))) u32*)(&As[buf][j * 4096 + sdst]),
            16, 0, 0);
    };
    auto stB = [&](int buf, int T, int j) {
        const u16* src = W + (size_t)(n0 + j * 64 + srow) * (size_t)K + kzoff + T * 64 + scol;
        __builtin_amdgcn_global_load_lds(
            (const __attribute__((address_space(1))) u32*)src,
            (__attribute__((address_space(3))) u32*)(&Bs[buf][j * 4096 + sdst]),
            16, 0, 0);
    };

    bf16x8 bfr[4];

    #define PH(BUF, KSL, MH, STMT, VMODE)                                         \
    do {                                                                          \
        if (MH == 0) {                                                            \
            _Pragma("unroll")                                                     \
            for (int ni = 0; ni < 4; ++ni)                                        \
                bfr[ni] = *(const bf16x8*)(&Bs[BUF][boffb + ni * 1024 + kswz[KSL]]); \
        }                                                                         \
        bf16x8 af0 = *(const bf16x8*)(&As[BUF][aoffb + (MH*4+0)*1024 + kswz[KSL]]);  \
        bf16x8 af1 = *(const bf16x8*)(&As[BUF][aoffb + (MH*4+1)*1024 + kswz[KSL]]);  \
        bf16x8 af2 = *(const bf16x8*)(&As[BUF][aoffb + (MH*4+2)*1024 + kswz[KSL]]);  \
        bf16x8 af3 = *(const bf16x8*)(&As[BUF][aoffb + (MH*4+3)*1024 + kswz[KSL]]);  \
        STMT;                                                                     \
        VMODE;                                                                    \
        __builtin_amdgcn_s_barrier();                                             \
        asm volatile("s_waitcnt lgkmcnt(0)" ::: "memory");                        \
        __builtin_amdgcn_sched_barrier(0);                                        \
        __builtin_amdgcn_s_setprio(1);                                            \
        _Pragma("unroll")                                                         \
        for (int ni = 0; ni < 4; ++ni) {                                          \
            acc[MH*4+0][ni] = __builtin_amdgcn_mfma_f32_16x16x32_bf16(af0, bfr[ni], acc[MH*4+0][ni], 0, 0, 0); \
            acc[MH*4+1][ni] = __builtin_amdgcn_mfma_f32_16x16x32_bf16(af1, bfr[ni], acc[MH*4+1][ni], 0, 0, 0); \
            acc[MH*4+2][ni] = __builtin_amdgcn_mfma_f32_16x16x32_bf16(af2, bfr[ni], acc[MH*4+2][ni], 0, 0, 0); \
            acc[MH*4+3][ni] = __builtin_amdgcn_mfma_f32_16x16x32_bf16(af3, bfr[ni], acc[MH*4+3][ni], 0, 0, 0); \
        }                                                                         \
        __builtin_amdgcn_s_setprio(0);                                            \
        __builtin_amdgcn_s_barrier();                                             \
    } while (0)

    #define VM_NONE do {} while (0)
    #define VM_P3   do { if (more) asm volatile("s_waitcnt vmcnt(2)" ::: "memory"); \
                         else      asm volatile("s_waitcnt vmcnt(0)" ::: "memory"); } while (0)
    #define VM_P7   do { if (more) asm volatile("s_waitcnt vmcnt(2)" ::: "memory"); } while (0)

    #pragma unroll
    for (int j = 0; j < 4; ++j) stB(0, 0, j);
    #pragma unroll
    for (int j = 0; j < 4; ++j) stA(0, 0, j);
    stB(1, 1, 0); stB(1, 1, 1);
    asm volatile("s_waitcnt vmcnt(2)" ::: "memory");
    __builtin_amdgcn_s_barrier();

    for (int it = 0; it < NI; ++it) {
        const bool more = (it + 1) < NI;
        const int T1 = 2 * it + 1, T2 = T1 + 1, T3 = T1 + 2;
        PH(0, 0, 0, { stB(1, T1, 2); stB(1, T1, 3); }, VM_NONE);
        PH(0, 0, 1, { stA(1, T1, 0); stA(1, T1, 1); }, VM_NONE);
        PH(0, 1, 0, { stA(1, T1, 2); stA(1, T1, 3); }, VM_NONE);
        PH(0, 1, 1, { if (more) { stB(0, T2, 0); stB(0, T2, 1); } }, VM_P3);
        PH(1, 0, 0, { if (more) { stB(0, T2, 2); stB(0, T2, 3); } }, VM_NONE);
        PH(1, 0, 1, { if (more) { stA(0, T2, 0); stA(0, T2, 1); } }, VM_NONE);
        PH(1, 1, 0, { if (more) { stA(0, T2, 2); stA(0, T2, 3); } }, VM_NONE);
        PH(1, 1, 1, { if (more) { stB(1, T3, 0); stB(1, T3, 1); } }, VM_P7);
    }
    #undef PH
    #undef VM_NONE
    #undef VM_P3
    #undef VM_P7

    // ---- coalesced epilogue via per-wave LDS transpose ----
    float* wsc = ((float*)&As[0][0]) + (size_t)w * (16 * 68);
    const int erow = lane >> 3;
    const int ecol = (lane & 7) * 4;
    float* Cfo = Cf;
    if (KS_ == 4)
        Cfo = (kz == 0) ? Cf : (kz == 1) ? Cf2 : (kz == 2) ? Cf3 : Cf4;
    #pragma unroll
    for (int mi = 0; mi < 8; ++mi) {
        #pragma unroll
        for (int ni = 0; ni < 4; ++ni)
            #pragma unroll
            for (int i = 0; i < 4; ++i)
                wsc[(q * 4 + i) * 68 + ni * 16 + r] = acc[mi][ni][i];
        asm volatile("s_waitcnt lgkmcnt(0)" ::: "memory");
        __builtin_amdgcn_sched_barrier(0);
        #pragma unroll
        for (int half = 0; half < 2; ++half) {
            #pragma unroll
            for (int k2 = 0; k2 < 2; ++k2) {
                int lr = half * 8 + erow;
                f32x4 v4 = *(const f32x4*)&wsc[lr * 68 + ecol + k2 * 32];
                int row = m0 + wm * 128 + mi * 16 + lr;
                int colb = n0 + wn * 64 + ecol + k2 * 32;
                size_t idx = (size_t)row * N + colb;
                if (EPI == 2) {
                    float4 bb = *(const float4*)&bias[colb];
                    float vv0 = v4[0] + bb.x, vv1 = v4[1] + bb.y;
                    float vv2 = v4[2] + bb.z, vv3 = v4[3] + bb.w;
                    u16x4 o;
                    #define GELU1(vx, slot) { \
                        float e = __expf(fminf(1.5957691216f * (vx) + 0.0713548162f * (vx)*(vx)*(vx), 80.f)); \
                        o[slot] = f2bf((vx) * __fdividef(e, e + 1.f)); }
                    GELU1(vv0, 0); GELU1(vv1, 1); GELU1(vv2, 2); GELU1(vv3, 3);
                    #undef GELU1
                    *(u16x4*)&Cb[idx] = o;
                } else {
                    *(f32x4*)&Cfo[idx] = v4;
                }
            }
        }
        asm volatile("s_waitcnt lgkmcnt(0)" ::: "memory");
        __builtin_amdgcn_sched_barrier(0);
    }
}

// ---------------- slim LN2: ln2_bf = LN(x2)*g + b ------------------------
__global__ __launch_bounds__(256) void ln2_kernel(
        const float* __restrict__ x2,
        const float* __restrict__ g, const float* __restrict__ b,
        u16* __restrict__ out_bf) {
    __shared__ float sm[4];
    int row = blockIdx.x;
    int t = threadIdx.x;
    size_t base = (size_t)row * DIMD + t * 4;
    float4 v = *(const float4*)(x2 + base);
    float s = v.x + v.y + v.z + v.w;
    for (int off = 32; off > 0; off >>= 1) s += __shfl_down(s, off, 64);
    if ((t & 63) == 0) sm[t >> 6] = s;
    __syncthreads();
    float mu = (sm[0] + sm[1] + sm[2] + sm[3]) * (1.0f / DIMD);
    float dx = v.x - mu, dy = v.y - mu, dz = v.z - mu, dw = v.w - mu;
    float ss = dx*dx + dy*dy + dz*dz + dw*dw;
    for (int off = 32; off > 0; off >>= 1) ss += __shfl_down(ss, off, 64);
    __syncthreads();
    if ((t & 63) == 0) sm[t >> 6] = ss;
    __syncthreads();
    float var = (sm[0] + sm[1] + sm[2] + sm[3]) * (1.0f / DIMD);
    float rs = rsqrtf(var + 1e-5f);
    float4 gv = ((const float4*)g)[t];
    float4 bv = ((const float4*)b)[t];
    u16* o = out_bf + base;
    o[0] = f2bf(dx * rs * gv.x + bv.x);
    o[1] = f2bf(dy * rs * gv.y + bv.y);
    o[2] = f2bf(dz * rs * gv.z + bv.z);
    o[3] = f2bf(dw * rs * gv.w + bv.w);
}

// ---------------- depthwise conv + SiLU, sliding window (8 l / thread) ---
__global__ __launch_bounds__(256) void conv_silu_kernel(
        const u16* __restrict__ xz,
        const float* __restrict__ wx, const float* __restrict__ bx,
        const float* __restrict__ wz, const float* __restrict__ bz,
        u16* __restrict__ u_bf, u16* __restrict__ ycat) {
    int c  = blockIdx.x * 256 + threadIdx.x;   // 0..1023
    int gy = blockIdx.y;                       // 0..NTOK/8-1
    int b  = gy >> 8;
    int l0 = (gy & 255) * 8;
    const u16* base = xz + ((size_t)(b * SEQ + l0)) * DINNER;
    float wxr[4], wzr[4];
    #pragma unroll
    for (int k = 0; k < 4; ++k) { wxr[k] = wx[c * 4 + k]; wzr[k] = wz[c * 4 + k]; }
    float bxv = bx[c], bzv = bz[c];
    float xm1 = (l0 > 0) ? bf2f(base[c - DINNER]) : 0.f;
    float x0v = bf2f(base[c]);
    float x1v = bf2f(base[c + DINNER]);
    float zm1 = (l0 > 0) ? bf2f(base[HALF + c - DINNER]) : 0.f;
    float z0v = bf2f(base[HALF + c]);
    float z1v = bf2f(base[HALF + c + DINNER]);
    u16* up = u_bf + ((size_t)(b * SEQ + l0)) * HALF + c;
    u16* yp = ycat + ((size_t)(b * SEQ + l0)) * DINNER + HALF + c;
    #pragma unroll
    for (int l = 0; l < 8; ++l) {
        bool in = (l0 + l + 2) < SEQ;
        float x2v = in ? bf2f(base[(size_t)(l + 2) * DINNER + c]) : 0.f;
        float z2v = in ? bf2f(base[(size_t)(l + 2) * DINNER + HALF + c]) : 0.f;
        float ax = bxv + wxr[0]*xm1 + wxr[1]*x0v + wxr[2]*x1v + wxr[3]*x2v;
        float az = bzv + wzr[0]*zm1 + wzr[1]*z0v + wzr[2]*z1v + wzr[3]*z2v;
        float sx = ax * __fdividef(1.f, 1.f + __expf(-ax));
        float sz = az * __fdividef(1.f, 1.f + __expf(-az));
        *up = f2bf(sx); *yp = f2bf(sz);
        up += HALF; yp += DINNER;
        xm1 = x0v; x0v = x1v; x1v = x2v;
        zm1 = z0v; z0v = z1v; z1v = z2v;
    }
}

// ---------------- chunk-parallel selective scan (thread per chain) -------
__global__ __launch_bounds__(256) void scan_p1_kernel(
        const float* __restrict__ delta, const u16* __restrict__ u_bf,
        const float* __restrict__ x_dbl, const float* __restrict__ A_log,
        float* __restrict__ hfin, float* __restrict__ dsum) {
    int t  = blockIdx.x * 256 + threadIdx.x;
    int d  = t & (HALF - 1);
    int ch = (t >> 10) & (NCH - 1);
    int b  = t >> 16;
    float Ac[16], h[16];
    #pragma unroll
    for (int i = 0; i < 4; ++i) {
        float4 a = *(const float4*)&A_log[d * DSTATE + i * 4];
        Ac[4*i+0] = -__expf(a.x); Ac[4*i+1] = -__expf(a.y);
        Ac[4*i+2] = -__expf(a.z); Ac[4*i+3] = -__expf(a.w);
        h[4*i+0] = 0.f; h[4*i+1] = 0.f; h[4*i+2] = 0.f; h[4*i+3] = 0.f;
    }
    int l0 = b * SEQ + ch * CL;
    size_t off = (size_t)l0 * HALF + d;
    const float* xrow = x_dbl + (size_t)l0 * 96;
    float ds = 0.f;
    #pragma unroll 4
    for (int l = 0; l < CL; ++l) {
        float dl = delta[off];
        float uv = bf2f(u_bf[off]);
        off += HALF;
        float4 B0 = *(const float4*)(xrow + 64);
        float4 B1 = *(const float4*)(xrow + 68);
        float4 B2 = *(const float4*)(xrow + 72);
        float4 B3 = *(const float4*)(xrow + 76);
        xrow += 96;
        float dBu = dl * uv;
        ds += dl;
        float Bv[16] = {B0.x,B0.y,B0.z,B0.w, B1.x,B1.y,B1.z,B1.w,
                        B2.x,B2.y,B2.z,B2.w, B3.x,B3.y,B3.z,B3.w};
        #pragma unroll
        for (int n = 0; n < 16; ++n)
            h[n] = __expf(dl * Ac[n]) * h[n] + dBu * Bv[n];
    }
    float4* hf = (float4*)&hfin[(size_t)t * 16];
    #pragma unroll
    for (int i = 0; i < 4; ++i)
        hf[i] = (float4){h[4*i+0], h[4*i+1], h[4*i+2], h[4*i+3]};
    dsum[t] = ds;
}

__global__ __launch_bounds__(256) void scan_p2_kernel(
        const float* __restrict__ A_log, const float* __restrict__ dsum,
        const float* __restrict__ hfin, float* __restrict__ hin) {
    int t = blockIdx.x * 256 + threadIdx.x;
    int n = t & 15;
    int d = (t >> 4) & (HALF - 1);
    int b = t >> 14;
    float Ac = -__expf(A_log[d * DSTATE + n]);
    float h = 0.f;
    for (int ch = 0; ch < NCH; ++ch) {
        size_t chain = ((size_t)(b * NCH + ch) * HALF) + d;
        hin[chain * 16 + n] = h;
        float ds = dsum[chain];
        h = __expf(Ac * ds) * h + hfin[chain * 16 + n];
    }
}

__global__ __launch_bounds__(256) void scan_p3_kernel(
        const float* __restrict__ delta, const u16* __restrict__ u_bf,
        const float* __restrict__ x_dbl, const float* __restrict__ A_log,
        const float* __restrict__ Dp, const float* __restrict__ hin,
        u16* __restrict__ ycat) {
    int t  = blockIdx.x * 256 + threadIdx.x;
    int d  = t & (HALF - 1);
    int ch = (t >> 10) & (NCH - 1);
    int b  = t >> 16;
    float Ac[16], h[16];
    #pragma unroll
    for (int i = 0; i < 4; ++i) {
        float4 a  = *(const float4*)&A_log[d * DSTATE + i * 4];
        float4 hv = *(const float4*)&hin[(size_t)t * 16 + i * 4];
        Ac[4*i+0] = -__expf(a.x); Ac[4*i+1] = -__expf(a.y);
        Ac[4*i+2] = -__expf(a.z); Ac[4*i+3] = -__expf(a.w);
        h[4*i+0] = hv.x; h[4*i+1] = hv.y; h[4*i+2] = hv.z; h[4*i+3] = hv.w;
    }
    float Dv = Dp[d];
    int l0 = b * SEQ + ch * CL;
    size_t off = (size_t)l0 * HALF + d;
    const float* xrow = x_dbl + (size_t)l0 * 96;
    u16* yp = ycat + (size_t)l0 * DINNER + d;
    #pragma unroll 4
    for (int l = 0; l < CL; ++l) {
        float dl = delta[off];
        float uv = bf2f(u_bf[off]);
        off += HALF;
        float4 B0 = *(const float4*)(xrow + 64);
        float4 B1 = *(const float4*)(xrow + 68);
        float4 B2 = *(const float4*)(xrow + 72);
        float4 B3 = *(const float4*)(xrow + 76);
        float4 C0 = *(const float4*)(xrow + 80);
        float4 C1 = *(const float4*)(xrow + 84);
        float4 C2 = *(const float4*)(xrow + 88);
        float4 C3 = *(const float4*)(xrow + 92);
        xrow += 96;
        float dBu = dl * uv;
        float Bv[16] = {B0.x,B0.y,B0.z,B0.w, B1.x,B1.y,B1.z,B1.w,
                        B2.x,B2.y,B2.z,B2.w, B3.x,B3.y,B3.z,B3.w};
        float Cv[16] = {C0.x,C0.y,C0.z,C0.w, C1.x,C1.y,C1.z,C1.w,
                        C2.x,C2.y,C2.z,C2.w, C3.x,C3.y,C3.z,C3.w};
        float y = uv * Dv;
        #pragma unroll
        for (int n = 0; n < 16; ++n) {
            h[n] = __expf(dl * Ac[n]) * h[n] + dBu * Bv[n];
            y += h[n] * Cv[n];
        }
        *yp = f2bf(y);
        yp += DINNER;
    }
}

// ---------------- host-side orchestration ----------------
extern "C" void kernel_launch(void* const* d_in, const int* in_sizes, int n_in,
                              void* d_out, int out_size, void* d_ws, size_t ws_size,
                              hipStream_t stream) {
    const float* x         = (const float*)d_in[0];
    const float* ln1_g     = (const float*)d_in[1];
    const float* ln1_b     = (const float*)d_in[2];
    const float* in_proj_w = (const float*)d_in[3];
    const float* conv_x_w  = (const float*)d_in[4];
    const float* conv_x_b  = (const float*)d_in[5];
    const float* conv_z_w  = (const float*)d_in[6];
    const float* conv_z_b  = (const float*)d_in[7];
    const float* x_proj_w  = (const float*)d_in[8];
    const float* dt_proj_w = (const float*)d_in[9];
    const float* dt_proj_b = (const float*)d_in[10];
    const float* A_log     = (const float*)d_in[11];
    const float* Dp        = (const float*)d_in[12];
    const float* out_proj_w= (const float*)d_in[13];
    const float* ln2_g     = (const float*)d_in[14];
    const float* ln2_b     = (const float*)d_in[15];
    const float* mlp_w1    = (const float*)d_in[16];
    const float* mlp_b1    = (const float*)d_in[17];
    const float* mlp_w2    = (const float*)d_in[18];
    const float* mlp_b2    = (const float*)d_in[19];
    float* out = (float*)d_out;

    char* p = (char*)d_ws;
    auto alloc = [&](size_t bytes) {
        char* r = p; p += (bytes + 255) & ~(size_t)255; return r;
    };
    u16*   w_in   = (u16*)  alloc((size_t)DINNER * DIMD * 2);
    u16*   w_xp   = (u16*)  alloc((size_t)96 * HALF * 2);
    u16*   w_dt   = (u16*)  alloc((size_t)HALF * DTRANK * 2);
    u16*   w_out  = (u16*)  alloc((size_t)DIMD * DINNER * 2);
    u16*   w_m1   = (u16*)  alloc((size_t)MLPD * DIMD * 2);
    u16*   w_m2   = (u16*)  alloc((size_t)DIMD * MLPD * 2);
    u16*   xn_bf  = (u16*)  alloc((size_t)NTOK * DIMD * 2);
    u16*   xz_bf  = (u16*)  alloc((size_t)NTOK * DINNER * 2);
    u16*   u_bf   = (u16*)  alloc((size_t)NTOK * HALF * 2);
    u16*   ycat   = (u16*)  alloc((size_t)NTOK * DINNER * 2);
    float* x_dbl  = (float*)alloc((size_t)NTOK * 96 * 4);
    u16*   xdbl_bf= (u16*)  alloc((size_t)NTOK * 96 * 2);
    float* delta  = (float*)alloc((size_t)NTOK * HALF * 4);
    float* x2     = (float*)alloc((size_t)NTOK * DIMD * 4);
    u16*   ln2_bf = (u16*)  alloc((size_t)NTOK * DIMD * 2);
    u16*   mlp_h  = (u16*)  alloc((size_t)NTOK * MLPD * 2);    // 32 MB
    // scan scratch aliases mlp_h (dead until mlp1):
    float* hfin = (float*)mlp_h;
    float* hin  = hfin + (size_t)BSZ * NCH * HALF * DSTATE;
    float* dsum = hin  + (size_t)BSZ * NCH * HALF * DSTATE;

    // fused LN1 + weight conversions
    cvtln_kernel<<<NTOK + CVT_BLOCKS, 256, 0, stream>>>(
        x, ln1_g, ln1_b, xn_bf,
        in_proj_w, w_in, x_proj_w, w_xp, dt_proj_w, w_dt,
        out_proj_w, w_out, mlp_w1, w_m1, mlp_w2, w_m2);

    // in_proj: xz_bf[4096,2048] = xn @ W^T (bf16 out, 2-phase 128x128)
    gemm128_kernel<5,128,1><<<dim3(NTOK/128, DINNER/128), 256, 0, stream>>>(
        xn_bf, DIMD, w_in, DIMD, DINNER, nullptr, nullptr,
        nullptr, nullptr, nullptr, nullptr, xz_bf);

    // depthwise conv + silu
    conv_silu_kernel<<<dim3(HALF/256, NTOK/8), 256, 0, stream>>>(
        xz_bf, conv_x_w, conv_x_b, conv_z_w, conv_z_b, u_bf, ycat);

    // x_proj
    gemm_small_kernel<<<dim3(NTOK/32, 96/16), 256, 0, stream>>>(
        u_bf, HALF, w_xp, HALF, 96, x_dbl, xdbl_bf);

    // dt_proj: delta = softplus(dt @ W^T + b)
    gemm128_kernel<1,64,1><<<dim3(NTOK/128, HALF/64), 256, 0, stream>>>(
        xdbl_bf, 96, w_dt, DTRANK, HALF, dt_proj_b, nullptr,
        delta, nullptr, nullptr, nullptr, nullptr);

    // chunk-parallel scan
    scan_p1_kernel<<<(BSZ*NCH*HALF)/256, 256, 0, stream>>>(
        delta, u_bf, x_dbl, A_log, hfin, dsum);
    scan_p2_kernel<<<(BSZ*HALF*DSTATE)/256, 256, 0, stream>>>(
        A_log, dsum, hfin, hin);
    scan_p3_kernel<<<(BSZ*NCH*HALF)/256, 256, 0, stream>>>(
        delta, u_bf, x_dbl, A_log, Dp, hin, ycat);

    // out_proj (no split-K, no reduce): x2 = ycat @ W^T + x
    // grid (32,16) = 512 blocks = 2/CU
    gemm128_kernel<3,64,1><<<dim3(NTOK/128, DIMD/64), 256, 0, stream>>>(
        ycat, DINNER, w_out, DINNER, DIMD, nullptr, x,
        x2, nullptr, nullptr, nullptr, nullptr);

    // slim LN2: ln2_bf = LN(x2)
    ln2_kernel<<<NTOK, 256, 0, stream>>>(x2, ln2_g, ln2_b, ln2_bf);

    // MLP1: 8-phase 256^2 + swizzle: gelu(ln2 @ W1^T + b1) -> bf16
    gemm256_kernel<2,1><<<dim3(NTOK/256, MLPD/256, 1), 512, 0, stream>>>(
        ln2_bf, DIMD, w_m1, DIMD, MLPD, mlp_b1,
        nullptr, nullptr, nullptr, nullptr, mlp_h);

    // MLP2 (no split-K, no reduce): out = mlp_h @ W2^T + b2 + x2
    gemm128_kernel<4,64,1><<<dim3(NTOK/128, DIMD/64), 256, 0, stream>>>(
        mlp_h, MLPD, w_m2, MLPD, DIMD, mlp_b2, x2,
        out, nullptr, nullptr, nullptr, nullptr);
}

// Round 11
// 397.093 us; speedup vs baseline: 1.9647x; 1.0121x over previous
//
#include <hip/hip_runtime.h>
#include <math.h>

#define DIMD    1024
#define MLPD    4096
#define DSTATE  16
#define DCONV   4
#define HALF    1024
#define DINNER  2048
#define DTRANK  64
#define BSZ     2
#define SEQ     2048
#define NTOK    (BSZ*SEQ)   // 4096
#define NCH     64
#define CL      (SEQ/NCH)   // 32

typedef short bf16x8 __attribute__((ext_vector_type(8)));
typedef float f32x4  __attribute__((ext_vector_type(4)));
typedef float f32x16 __attribute__((ext_vector_type(16)));
typedef unsigned short u16;
typedef unsigned int   u32;
typedef unsigned short u16x4 __attribute__((ext_vector_type(4)));

__device__ __forceinline__ u16 f2bf(float x) {
    union { float f; unsigned int u; } v; v.f = x;
    unsigned int r = (v.u + 0x7FFFu + ((v.u >> 16) & 1u)) >> 16;
    return (u16)r;
}
__device__ __forceinline__ float bf2f(u16 x) {
    union { unsigned int u; float f; } v; v.u = ((unsigned int)x) << 16;
    return v.f;
}

// ---------------- fused LN1 + weight f32->bf16 convert -------------------
#define SZ_WIN  (DINNER*DIMD)
#define SZ_WXP  (96*HALF)
#define SZ_WDT  (HALF*DTRANK)
#define SZ_WOUT (DIMD*DINNER)
#define SZ_WM1  (MLPD*DIMD)
#define SZ_WM2  (DIMD*MLPD)
#define SZ_TOT  (SZ_WIN+SZ_WXP+SZ_WDT+SZ_WOUT+SZ_WM1+SZ_WM2)
#define CVT_BLOCKS (SZ_TOT / 1024)

__global__ __launch_bounds__(256) void cvtln_kernel(
        const float* __restrict__ x, const float* __restrict__ g,
        const float* __restrict__ b, u16* __restrict__ xn_bf,
        const float* __restrict__ s0, u16* __restrict__ d0,
        const float* __restrict__ s1, u16* __restrict__ d1,
        const float* __restrict__ s2, u16* __restrict__ d2,
        const float* __restrict__ s3, u16* __restrict__ d3,
        const float* __restrict__ s4, u16* __restrict__ d4,
        const float* __restrict__ s5, u16* __restrict__ d5) {
    if (blockIdx.x >= NTOK) {
        int i = (blockIdx.x - NTOK) * 1024 + threadIdx.x * 4;
        #define CVT4(s, d) { \
            float4 v = *(const float4*)((s) + i); \
            u16x4 o; o[0]=f2bf(v.x); o[1]=f2bf(v.y); o[2]=f2bf(v.z); o[3]=f2bf(v.w); \
            *(u16x4*)((d) + i) = o; }
        if (i < SZ_WIN)  { CVT4(s0, d0); return; }  i -= SZ_WIN;
        if (i < SZ_WXP)  { CVT4(s1, d1); return; }  i -= SZ_WXP;
        if (i < SZ_WDT)  { CVT4(s2, d2); return; }  i -= SZ_WDT;
        if (i < SZ_WOUT) { CVT4(s3, d3); return; }  i -= SZ_WOUT;
        if (i < SZ_WM1)  { CVT4(s4, d4); return; }  i -= SZ_WM1;
        if (i < SZ_WM2)  { CVT4(s5, d5); }
        #undef CVT4
        return;
    }
    __shared__ float sm[4];
    int row = blockIdx.x;
    int t = threadIdx.x;
    const float4* xr = (const float4*)(x + (size_t)row * DIMD);
    float4 v = xr[t];
    float s = v.x + v.y + v.z + v.w;
    for (int off = 32; off > 0; off >>= 1) s += __shfl_down(s, off, 64);
    if ((t & 63) == 0) sm[t >> 6] = s;
    __syncthreads();
    float mu = (sm[0] + sm[1] + sm[2] + sm[3]) * (1.0f / DIMD);
    float dx = v.x - mu, dy = v.y - mu, dz = v.z - mu, dw = v.w - mu;
    float ss = dx*dx + dy*dy + dz*dz + dw*dw;
    for (int off = 32; off > 0; off >>= 1) ss += __shfl_down(ss, off, 64);
    __syncthreads();
    if ((t & 63) == 0) sm[t >> 6] = ss;
    __syncthreads();
    float var = (sm[0] + sm[1] + sm[2] + sm[3]) * (1.0f / DIMD);
    float rs = rsqrtf(var + 1e-5f);
    float4 gv = ((const float4*)g)[t];
    float4 bv = ((const float4*)b)[t];
    u16* o = xn_bf + (size_t)row * DIMD + t * 4;
    o[0] = f2bf(dx * rs * gv.x + bv.x);
    o[1] = f2bf(dy * rs * gv.y + bv.y);
    o[2] = f2bf(dz * rs * gv.z + bv.z);
    o[3] = f2bf(dw * rs * gv.w + bv.w);
}

// ---------------- x_proj GEMM: 4 waves = 2 m-tiles x 2 K-halves ----------
__global__ __launch_bounds__(256) void gemm_small_kernel(
        const u16* __restrict__ A, int lda,
        const u16* __restrict__ W, int K, int N,
        float* __restrict__ Cf, u16* __restrict__ Cb) {
    __shared__ f32x4 red[2][64];
    int t = threadIdx.x;
    int w = t >> 6, lane = t & 63;
    int mt = w & 1, kh = w >> 1;
    int m0 = blockIdx.x * 32 + mt * 16;
    int n0 = blockIdx.y * 16;
    int r = lane & 15, quad = lane >> 4;
    int Kh = K >> 1;
    f32x4 acc = {0.f, 0.f, 0.f, 0.f};
    const u16* ap = A + (size_t)(m0 + r) * lda + kh * Kh + quad * 8;
    const u16* wp = W + (size_t)(n0 + r) * K   + kh * Kh + quad * 8;
    for (int k = 0; k < Kh; k += 32) {
        bf16x8 av = *(const bf16x8*)(ap + k);
        bf16x8 bv = *(const bf16x8*)(wp + k);
        acc = __builtin_amdgcn_mfma_f32_16x16x32_bf16(av, bv, acc, 0, 0, 0);
    }
    if (kh == 1) red[mt][lane] = acc;
    __syncthreads();
    if (kh == 0) {
        f32x4 o = red[mt][lane];
        int col = n0 + r;
        #pragma unroll
        for (int i = 0; i < 4; ++i) {
            int row = m0 + quad * 4 + i;
            size_t idx = (size_t)row * N + col;
            float v = acc[i] + o[i];
            Cf[idx] = v;
            Cb[idx] = f2bf(v);
        }
    }
}

// ---------------- 2-phase 128xTN GEMM (in_proj only now) -----------------
// EPI: 5 plain bf16
template<int EPI, int TN, int KS>
__global__ __launch_bounds__(256) void gemm128_kernel(
        const u16* __restrict__ A, int lda, const u16* __restrict__ W,
        int K, int N,
        const float* __restrict__ bias, const float* __restrict__ resid,
        float* __restrict__ Cf, float* __restrict__ Cf2,
        float* __restrict__ Cf3, float* __restrict__ Cf4,
        u16* __restrict__ Cb) {
    constexpr int NF = TN / 32;
    constexpr int NN = TN / 64;
    __shared__ u16 As0[128 * 32], As1[128 * 32];
    __shared__ u16 Bs0[TN * 32],  Bs1[TN * 32];
    const int t = threadIdx.x;
    const int w = t >> 6;
    const int lane = t & 63;
    const int r32 = lane & 31;
    const int kh  = lane >> 5;
    const int wm = w & 1, wn = w >> 1;
    const int m0 = blockIdx.x * 128;
    const int n0 = blockIdx.y * TN;
    const int Kloc = K / KS;
    const int kz = (KS > 1) ? blockIdx.z : 0;

    f32x16 acc[2][NN];
    #pragma unroll
    for (int mi = 0; mi < 2; ++mi)
        #pragma unroll
        for (int ni = 0; ni < NN; ++ni)
            acc[mi][ni] = (f32x16){0.f,0.f,0.f,0.f,0.f,0.f,0.f,0.f,
                                   0.f,0.f,0.f,0.f,0.f,0.f,0.f,0.f};

    const u16* pa[2];
    const u16* pb[NF / 2];
    #pragma unroll
    for (int i = 0; i < 2; ++i) {
        int c = (i * 4 + w) * 64 + lane;
        int row = c >> 2;
        int q = (c & 3) ^ ((row >> 1) & 3);
        pa[i] = A + (size_t)(m0 + row) * lda + (size_t)kz * Kloc + q * 8;
    }
    #pragma unroll
    for (int i = 0; i < NF / 2; ++i) {
        int c = (i * 4 + w) * 64 + lane;
        int row = c >> 2;
        int q = (c & 3) ^ ((row >> 1) & 3);
        pb[i] = W + (size_t)(n0 + row) * K + (size_t)kz * Kloc + q * 8;
    }
    const int gsw = (r32 >> 1) & 3;
    int aoff[2][2], boff[NN][2];
    #pragma unroll
    for (int mi = 0; mi < 2; ++mi)
        #pragma unroll
        for (int tt = 0; tt < 2; ++tt)
            aoff[mi][tt] = (wm * 64 + mi * 32 + r32) * 32 +
                           ((tt * 2 + kh) ^ gsw) * 8;
    #pragma unroll
    for (int ni = 0; ni < NN; ++ni)
        #pragma unroll
        for (int tt = 0; tt < 2; ++tt)
            boff[ni][tt] = (wn * (TN / 2) + ni * 32 + r32) * 32 +
                           ((tt * 2 + kh) ^ gsw) * 8;

    auto stage = [&](u16* __restrict__ Ad, u16* __restrict__ Bd) {
        #pragma unroll
        for (int i = 0; i < 2; ++i) {
            __builtin_amdgcn_global_load_lds(
                (const __attribute__((address_space(1))) u32*)pa[i],
                (__attribute__((address_space(3))) u32*)(Ad + (i * 4 + w) * 512),
                16, 0, 0);
            pa[i] += 32;
        }
        #pragma unroll
        for (int i = 0; i < NF / 2; ++i) {
            __builtin_amdgcn_global_load_lds(
                (const __attribute__((address_space(1))) u32*)pb[i],
                (__attribute__((address_space(3))) u32*)(Bd + (i * 4 + w) * 512),
                16, 0, 0);
            pb[i] += 32;
        }
    };
    auto compute = [&](const u16* __restrict__ Ab, const u16* __restrict__ Bb) {
        bf16x8 af[2][2], bfr[NN][2];
        #pragma unroll
        for (int mi = 0; mi < 2; ++mi)
            #pragma unroll
            for (int tt = 0; tt < 2; ++tt)
                af[mi][tt] = *(const bf16x8*)(Ab + aoff[mi][tt]);
        #pragma unroll
        for (int ni = 0; ni < NN; ++ni)
            #pragma unroll
            for (int tt = 0; tt < 2; ++tt)
                bfr[ni][tt] = *(const bf16x8*)(Bb + boff[ni][tt]);
        #pragma unroll
        for (int tt = 0; tt < 2; ++tt)
            #pragma unroll
            for (int mi = 0; mi < 2; ++mi)
                #pragma unroll
                for (int ni = 0; ni < NN; ++ni)
                    acc[mi][ni] = __builtin_amdgcn_mfma_f32_32x32x16_bf16(
                        af[mi][tt], bfr[ni][tt], acc[mi][ni], 0, 0, 0);
    };

    stage(As0, Bs0);
    for (int k0 = 0; k0 < Kloc; k0 += 64) {
        __syncthreads();
        if (k0 + 32 < Kloc) stage(As1, Bs1);
        compute(As0, Bs0);
        __syncthreads();
        if (k0 + 64 < Kloc) stage(As0, Bs0);
        compute(As1, Bs1);
    }

    float* Cfo = Cf;
    if (KS == 2 && kz == 1) Cfo = Cf2;
    if (KS == 4) Cfo = (kz == 0) ? Cf : (kz == 1) ? Cf2 : (kz == 2) ? Cf3 : Cf4;
    #pragma unroll
    for (int mi = 0; mi < 2; ++mi) {
        #pragma unroll
        for (int ni = 0; ni < NN; ++ni) {
            #pragma unroll
            for (int reg = 0; reg < 16; ++reg) {
                int row = m0 + wm * 64 + mi * 32 + (reg & 3) + 8 * (reg >> 2) + 4 * kh;
                int col = n0 + wn * (TN / 2) + ni * 32 + r32;
                size_t idx = (size_t)row * N + col;
                float v = acc[mi][ni][reg];
                if (EPI == 1) { v += bias[col]; v = (v > 20.f) ? v : log1pf(expf(v)); }
                if (EPI == 2) {
                    v += bias[col];
                    float e = __expf(fminf(1.5957691216f * v + 0.0713548162f * v * v * v, 80.f));
                    v = v * __fdividef(e, e + 1.f);
                }
                if (EPI == 3) { v += resid[idx]; }
                if (EPI == 4) { v += bias[col] + resid[idx]; }
                if (EPI == 2 || EPI == 5) Cb[idx] = f2bf(v);
                else                      Cfo[idx] = v;
            }
        }
    }
}

// ---------------- 2-phase 128x64 GEMM, BK=64 (dt_proj/out_proj/MLP2) -----
// Halves barrier count vs BK=32 (one barrier-pair per 64 K), full 8-pos
// granule XOR swizzle (conflict-free ds_read_b128). LDS 48 KB.
// EPI: 1 bias+softplus f32 | 3 +resid f32 | 4 bias+resid f32
template<int EPI>
__global__ __launch_bounds__(256) void gemm64_kernel(
        const u16* __restrict__ A, int lda, const u16* __restrict__ W,
        int K, int N,
        const float* __restrict__ bias, const float* __restrict__ resid,
        float* __restrict__ Cf) {
    __shared__ u16 As0[128 * 64], As1[128 * 64];
    __shared__ u16 Bs0[64 * 64],  Bs1[64 * 64];
    const int t = threadIdx.x;
    const int w = t >> 6;
    const int lane = t & 63;
    const int r32 = lane & 31;
    const int kh  = lane >> 5;
    const int wm = w & 1, wn = w >> 1;
    const int m0 = blockIdx.x * 128;
    const int n0 = blockIdx.y * 64;

    f32x16 acc[2];
    acc[0] = (f32x16){0.f,0.f,0.f,0.f,0.f,0.f,0.f,0.f,
                      0.f,0.f,0.f,0.f,0.f,0.f,0.f,0.f};
    acc[1] = acc[0];

    // staging: call i covers 32 rows; thread t -> row i*32+(t>>3),
    // LDS granule t&7 holds global granule (t&7)^(row&7) (row&7=(t>>3)&7).
    const int srow = t >> 3;
    const int sgr  = ((t & 7) ^ (srow & 7)) * 8;
    const u16* pa[4];
    const u16* pb[2];
    #pragma unroll
    for (int i = 0; i < 4; ++i)
        pa[i] = A + (size_t)(m0 + i * 32 + srow) * lda + sgr;
    #pragma unroll
    for (int i = 0; i < 2; ++i)
        pb[i] = W + (size_t)(n0 + i * 32 + srow) * K + sgr;

    // read: elem = row*64 + ((tt*2+kh)^(row&7))*8 ; row&7 == r32&7 (lane-const)
    const int ksw = r32 & 7;
    int aoff[2][4], boff[4];
    #pragma unroll
    for (int mi = 0; mi < 2; ++mi)
        #pragma unroll
        for (int tt = 0; tt < 4; ++tt)
            aoff[mi][tt] = (wm * 64 + mi * 32 + r32) * 64 +
                           ((tt * 2 + kh) ^ ksw) * 8;
    #pragma unroll
    for (int tt = 0; tt < 4; ++tt)
        boff[tt] = (wn * 32 + r32) * 64 + ((tt * 2 + kh) ^ ksw) * 8;

    auto stage = [&](u16* __restrict__ Ad, u16* __restrict__ Bd) {
        #pragma unroll
        for (int i = 0; i < 4; ++i) {
            __builtin_amdgcn_global_load_lds(
                (const __attribute__((address_space(1))) u32*)pa[i],
                (__attribute__((address_space(3))) u32*)(Ad + i * 2048 + (t >> 6) * 512),
                16, 0, 0);
            pa[i] += 64;
        }
        #pragma unroll
        for (int i = 0; i < 2; ++i) {
            __builtin_amdgcn_global_load_lds(
                (const __attribute__((address_space(1))) u32*)pb[i],
                (__attribute__((address_space(3))) u32*)(Bd + i * 2048 + (t >> 6) * 512),
                16, 0, 0);
            pb[i] += 64;
        }
    };
    auto compute = [&](const u16* __restrict__ Ab, const u16* __restrict__ Bb) {
        bf16x8 af[2][4], bfr[4];
        #pragma unroll
        for (int mi = 0; mi < 2; ++mi)
            #pragma unroll
            for (int tt = 0; tt < 4; ++tt)
                af[mi][tt] = *(const bf16x8*)(Ab + aoff[mi][tt]);
        #pragma unroll
        for (int tt = 0; tt < 4; ++tt)
            bfr[tt] = *(const bf16x8*)(Bb + boff[tt]);
        #pragma unroll
        for (int tt = 0; tt < 4; ++tt)
            #pragma unroll
            for (int mi = 0; mi < 2; ++mi)
                acc[mi] = __builtin_amdgcn_mfma_f32_32x32x16_bf16(
                    af[mi][tt], bfr[tt], acc[mi], 0, 0, 0);
    };

    stage(As0, Bs0);
    for (int k0 = 0; k0 < K; k0 += 128) {
        __syncthreads();
        if (k0 + 64 < K) stage(As1, Bs1);
        compute(As0, Bs0);
        if (k0 + 64 < K) {
            __syncthreads();
            if (k0 + 128 < K) stage(As0, Bs0);
            compute(As1, Bs1);
        }
    }

    // C/D 32x32 layout: col = lane&31, row = (reg&3)+8*(reg>>2)+4*kh
    #pragma unroll
    for (int mi = 0; mi < 2; ++mi) {
        #pragma unroll
        for (int reg = 0; reg < 16; ++reg) {
            int row = m0 + wm * 64 + mi * 32 + (reg & 3) + 8 * (reg >> 2) + 4 * kh;
            int col = n0 + wn * 32 + r32;
            size_t idx = (size_t)row * N + col;
            float v = acc[mi][reg];
            if (EPI == 1) { v += bias[col]; v = (v > 20.f) ? v : log1pf(expf(v)); }
            if (EPI == 3) { v += resid[idx]; }
            if (EPI == 4) { v += bias[col] + resid[idx]; }
            Cf[idx] = v;
        }
    }
}

// ---------------- 8-phase 256x256 GEMM (MLP1) ----------------------------
// 512 threads = 8 waves (2M x 4N); BK=64; XOR-swizzled LDS double-buffer;
// counted vmcnt(2) at phases 3/7; coalesced epilogue.
// EPI: 0 f32 partial | 2 bias+gelu -> bf16
template<int EPI, int KS_>
__global__ __launch_bounds__(512) void gemm256_kernel(
        const u16* __restrict__ A, int lda, const u16* __restrict__ W,
        int K, int N,
        const float* __restrict__ bias,
        float* __restrict__ Cf, float* __restrict__ Cf2,
        float* __restrict__ Cf3, float* __restrict__ Cf4,
        u16* __restrict__ Cb) {
    __shared__ u16 As[2][256 * 64];   // [buf][row*64 + swizzled col]
    __shared__ u16 Bs[2][256 * 64];
    const int t = threadIdx.x;
    const int lane = t & 63;
    const int w = t >> 6;
    const int r = lane & 15, q = lane >> 4;
    const int wm = w >> 2, wn = w & 3;           // 2 x 4 wave grid
    const int m0 = blockIdx.x * 256;
    const int n0 = blockIdx.y * 256;
    const int kz = (KS_ > 1) ? blockIdx.z : 0;
    const int Kloc = K / KS_;
    const int NI = Kloc / 128;                   // iters (2 K-tiles of 64 each)

    f32x4 acc[8][4];
    #pragma unroll
    for (int mi = 0; mi < 8; ++mi)
        #pragma unroll
        for (int ni = 0; ni < 4; ++ni)
            acc[mi][ni] = (f32x4){0.f, 0.f, 0.f, 0.f};

    const int aoffb = (wm * 128 + r) * 64;
    const int boffb = (wn * 64  + r) * 64;
    const int kswz[2] = { ((0 + q) ^ (r & 7)) * 8,
                          ((4 + q) ^ (r & 7)) * 8 };
    const int srow = t >> 3;
    const int scol = (((t & 7) ^ (srow & 7)) * 8);
    const int sdst = (t >> 6) * 512;
    const size_t kzoff = (size_t)kz * Kloc;

    auto stA = [&](int buf, int T, int j) {
        const u16* src = A + (size_t)(m0 + j * 64 + srow) * lda + kzoff + T * 64 + scol;
        __builtin_amdgcn_global_load_lds(
            (const __attribute__((address_space(1))) u32*)src,
            (__attribute__((address_space(3))) u32*)(&As[buf][j * 4096 + sdst]),
            16, 0, 0);
    };
    auto stB = [&](int buf, int T, int j) {
        const u16* src = W + (size_t)(n0 + j * 64 + srow) * (size_t)K + kzoff + T * 64 + scol;
        __builtin_amdgcn_global_load_lds(
            (const __attribute__((address_space(1))) u32*)src,
            (__attribute__((address_space(3))) u32*)(&Bs[buf][j * 4096 + sdst]),
            16, 0, 0);
    };

    bf16x8 bfr[4];

    #define PH(BUF, KSL, MH, STMT, VMODE)                                         \
    do {                                                                          \
        if (MH == 0) {                                                            \
            _Pragma("unroll")                                                     \
            for (int ni = 0; ni < 4; ++ni)                                        \
                bfr[ni] = *(const bf16x8*)(&Bs[BUF][boffb + ni * 1024 + kswz[KSL]]); \
        }                                                                         \
        bf16x8 af0 = *(const bf16x8*)(&As[BUF][aoffb + (MH*4+0)*1024 + kswz[KSL]]);  \
        bf16x8 af1 = *(const bf16x8*)(&As[BUF][aoffb + (MH*4+1)*1024 + kswz[KSL]]);  \
        bf16x8 af2 = *(const bf16x8*)(&As[BUF][aoffb + (MH*4+2)*1024 + kswz[KSL]]);  \
        bf16x8 af3 = *(const bf16x8*)(&As[BUF][aoffb + (MH*4+3)*1024 + kswz[KSL]]);  \
        STMT;                                                                     \
        VMODE;                                                                    \
        __builtin_amdgcn_s_barrier();                                             \
        asm volatile("s_waitcnt lgkmcnt(0)" ::: "memory");                        \
        __builtin_amdgcn_sched_barrier(0);                                        \
        __builtin_amdgcn_s_setprio(1);                                            \
        _Pragma("unroll")                                                         \
        for (int ni = 0; ni < 4; ++ni) {                                          \
            acc[MH*4+0][ni] = __builtin_amdgcn_mfma_f32_16x16x32_bf16(af0, bfr[ni], acc[MH*4+0][ni], 0, 0, 0); \
            acc[MH*4+1][ni] = __builtin_amdgcn_mfma_f32_16x16x32_bf16(af1, bfr[ni], acc[MH*4+1][ni], 0, 0, 0); \
            acc[MH*4+2][ni] = __builtin_amdgcn_mfma_f32_16x16x32_bf16(af2, bfr[ni], acc[MH*4+2][ni], 0, 0, 0); \
            acc[MH*4+3][ni] = __builtin_amdgcn_mfma_f32_16x16x32_bf16(af3, bfr[ni], acc[MH*4+3][ni], 0, 0, 0); \
        }                                                                         \
        __builtin_amdgcn_s_setprio(0);                                            \
        __builtin_amdgcn_s_barrier();                                             \
    } while (0)

    #define VM_NONE do {} while (0)
    #define VM_P3   do { if (more) asm volatile("s_waitcnt vmcnt(2)" ::: "memory"); \
                         else      asm volatile("s_waitcnt vmcnt(0)" ::: "memory"); } while (0)
    #define VM_P7   do { if (more) asm volatile("s_waitcnt vmcnt(2)" ::: "memory"); } while (0)

    #pragma unroll
    for (int j = 0; j < 4; ++j) stB(0, 0, j);
    #pragma unroll
    for (int j = 0; j < 4; ++j) stA(0, 0, j);
    stB(1, 1, 0); stB(1, 1, 1);
    asm volatile("s_waitcnt vmcnt(2)" ::: "memory");
    __builtin_amdgcn_s_barrier();

    for (int it = 0; it < NI; ++it) {
        const bool more = (it + 1) < NI;
        const int T1 = 2 * it + 1, T2 = T1 + 1, T3 = T1 + 2;
        PH(0, 0, 0, { stB(1, T1, 2); stB(1, T1, 3); }, VM_NONE);
        PH(0, 0, 1, { stA(1, T1, 0); stA(1, T1, 1); }, VM_NONE);
        PH(0, 1, 0, { stA(1, T1, 2); stA(1, T1, 3); }, VM_NONE);
        PH(0, 1, 1, { if (more) { stB(0, T2, 0); stB(0, T2, 1); } }, VM_P3);
        PH(1, 0, 0, { if (more) { stB(0, T2, 2); stB(0, T2, 3); } }, VM_NONE);
        PH(1, 0, 1, { if (more) { stA(0, T2, 0); stA(0, T2, 1); } }, VM_NONE);
        PH(1, 1, 0, { if (more) { stA(0, T2, 2); stA(0, T2, 3); } }, VM_NONE);
        PH(1, 1, 1, { if (more) { stB(1, T3, 0); stB(1, T3, 1); } }, VM_P7);
    }
    #undef PH
    #undef VM_NONE
    #undef VM_P3
    #undef VM_P7

    // ---- coalesced epilogue via per-wave LDS transpose ----
    float* wsc = ((float*)&As[0][0]) + (size_t)w * (16 * 68);
    const int erow = lane >> 3;
    const int ecol = (lane & 7) * 4;
    float* Cfo = Cf;
    if (KS_ == 4)
        Cfo = (kz == 0) ? Cf : (kz == 1) ? Cf2 : (kz == 2) ? Cf3 : Cf4;
    #pragma unroll
    for (int mi = 0; mi < 8; ++mi) {
        #pragma unroll
        for (int ni = 0; ni < 4; ++ni)
            #pragma unroll
            for (int i = 0; i < 4; ++i)
                wsc[(q * 4 + i) * 68 + ni * 16 + r] = acc[mi][ni][i];
        asm volatile("s_waitcnt lgkmcnt(0)" ::: "memory");
        __builtin_amdgcn_sched_barrier(0);
        #pragma unroll
        for (int half = 0; half < 2; ++half) {
            #pragma unroll
            for (int k2 = 0; k2 < 2; ++k2) {
                int lr = half * 8 + erow;
                f32x4 v4 = *(const f32x4*)&wsc[lr * 68 + ecol + k2 * 32];
                int row = m0 + wm * 128 + mi * 16 + lr;
                int colb = n0 + wn * 64 + ecol + k2 * 32;
                size_t idx = (size_t)row * N + colb;
                if (EPI == 2) {
                    float4 bb = *(const float4*)&bias[colb];
                    float vv0 = v4[0] + bb.x, vv1 = v4[1] + bb.y;
                    float vv2 = v4[2] + bb.z, vv3 = v4[3] + bb.w;
                    u16x4 o;
                    #define GELU1(vx, slot) { \
                        float e = __expf(fminf(1.5957691216f * (vx) + 0.0713548162f * (vx)*(vx)*(vx), 80.f)); \
                        o[slot] = f2bf((vx) * __fdividef(e, e + 1.f)); }
                    GELU1(vv0, 0); GELU1(vv1, 1); GELU1(vv2, 2); GELU1(vv3, 3);
                    #undef GELU1
                    *(u16x4*)&Cb[idx] = o;
                } else {
                    *(f32x4*)&Cfo[idx] = v4;
                }
            }
        }
        asm volatile("s_waitcnt lgkmcnt(0)" ::: "memory");
        __builtin_amdgcn_sched_barrier(0);
    }
}

// ---------------- slim LN2: ln2_bf = LN(x2)*g + b ------------------------
__global__ __launch_bounds__(256) void ln2_kernel(
        const float* __restrict__ x2,
        const float* __restrict__ g, const float* __restrict__ b,
        u16* __restrict__ out_bf) {
    __shared__ float sm[4];
    int row = blockIdx.x;
    int t = threadIdx.x;
    size_t base = (size_t)row * DIMD + t * 4;
    float4 v = *(const float4*)(x2 + base);
    float s = v.x + v.y + v.z + v.w;
    for (int off = 32; off > 0; off >>= 1) s += __shfl_down(s, off, 64);
    if ((t & 63) == 0) sm[t >> 6] = s;
    __syncthreads();
    float mu = (sm[0] + sm[1] + sm[2] + sm[3]) * (1.0f / DIMD);
    float dx = v.x - mu, dy = v.y - mu, dz = v.z - mu, dw = v.w - mu;
    float ss = dx*dx + dy*dy + dz*dz + dw*dw;
    for (int off = 32; off > 0; off >>= 1) ss += __shfl_down(ss, off, 64);
    __syncthreads();
    if ((t & 63) == 0) sm[t >> 6] = ss;
    __syncthreads();
    float var = (sm[0] + sm[1] + sm[2] + sm[3]) * (1.0f / DIMD);
    float rs = rsqrtf(var + 1e-5f);
    float4 gv = ((const float4*)g)[t];
    float4 bv = ((const float4*)b)[t];
    u16* o = out_bf + base;
    o[0] = f2bf(dx * rs * gv.x + bv.x);
    o[1] = f2bf(dy * rs * gv.y + bv.y);
    o[2] = f2bf(dz * rs * gv.z + bv.z);
    o[3] = f2bf(dw * rs * gv.w + bv.w);
}

// ---------------- depthwise conv + SiLU, sliding window (8 l / thread) ---
__global__ __launch_bounds__(256) void conv_silu_kernel(
        const u16* __restrict__ xz,
        const float* __restrict__ wx, const float* __restrict__ bx,
        const float* __restrict__ wz, const float* __restrict__ bz,
        u16* __restrict__ u_bf, u16* __restrict__ ycat) {
    int c  = blockIdx.x * 256 + threadIdx.x;   // 0..1023
    int gy = blockIdx.y;                       // 0..NTOK/8-1
    int b  = gy >> 8;
    int l0 = (gy & 255) * 8;
    const u16* base = xz + ((size_t)(b * SEQ + l0)) * DINNER;
    float wxr[4], wzr[4];
    #pragma unroll
    for (int k = 0; k < 4; ++k) { wxr[k] = wx[c * 4 + k]; wzr[k] = wz[c * 4 + k]; }
    float bxv = bx[c], bzv = bz[c];
    float xm1 = (l0 > 0) ? bf2f(base[c - DINNER]) : 0.f;
    float x0v = bf2f(base[c]);
    float x1v = bf2f(base[c + DINNER]);
    float zm1 = (l0 > 0) ? bf2f(base[HALF + c - DINNER]) : 0.f;
    float z0v = bf2f(base[HALF + c]);
    float z1v = bf2f(base[HALF + c + DINNER]);
    u16* up = u_bf + ((size_t)(b * SEQ + l0)) * HALF + c;
    u16* yp = ycat + ((size_t)(b * SEQ + l0)) * DINNER + HALF + c;
    #pragma unroll
    for (int l = 0; l < 8; ++l) {
        bool in = (l0 + l + 2) < SEQ;
        float x2v = in ? bf2f(base[(size_t)(l + 2) * DINNER + c]) : 0.f;
        float z2v = in ? bf2f(base[(size_t)(l + 2) * DINNER + HALF + c]) : 0.f;
        float ax = bxv + wxr[0]*xm1 + wxr[1]*x0v + wxr[2]*x1v + wxr[3]*x2v;
        float az = bzv + wzr[0]*zm1 + wzr[1]*z0v + wzr[2]*z1v + wzr[3]*z2v;
        float sx = ax * __fdividef(1.f, 1.f + __expf(-ax));
        float sz = az * __fdividef(1.f, 1.f + __expf(-az));
        *up = f2bf(sx); *yp = f2bf(sz);
        up += HALF; yp += DINNER;
        xm1 = x0v; x0v = x1v; x1v = x2v;
        zm1 = z0v; z0v = z1v; z1v = z2v;
    }
}

// ---------------- chunk-parallel selective scan (thread per chain) -------
__global__ __launch_bounds__(256) void scan_p1_kernel(
        const float* __restrict__ delta, const u16* __restrict__ u_bf,
        const float* __restrict__ x_dbl, const float* __restrict__ A_log,
        float* __restrict__ hfin, float* __restrict__ dsum) {
    int t  = blockIdx.x * 256 + threadIdx.x;
    int d  = t & (HALF - 1);
    int ch = (t >> 10) & (NCH - 1);
    int b  = t >> 16;
    float Ac[16], h[16];
    #pragma unroll
    for (int i = 0; i < 4; ++i) {
        float4 a = *(const float4*)&A_log[d * DSTATE + i * 4];
        Ac[4*i+0] = -__expf(a.x); Ac[4*i+1] = -__expf(a.y);
        Ac[4*i+2] = -__expf(a.z); Ac[4*i+3] = -__expf(a.w);
        h[4*i+0] = 0.f; h[4*i+1] = 0.f; h[4*i+2] = 0.f; h[4*i+3] = 0.f;
    }
    int l0 = b * SEQ + ch * CL;
    size_t off = (size_t)l0 * HALF + d;
    const float* xrow = x_dbl + (size_t)l0 * 96;
    float ds = 0.f;
    #pragma unroll 4
    for (int l = 0; l < CL; ++l) {
        float dl = delta[off];
        float uv = bf2f(u_bf[off]);
        off += HALF;
        float4 B0 = *(const float4*)(xrow + 64);
        float4 B1 = *(const float4*)(xrow + 68);
        float4 B2 = *(const float4*)(xrow + 72);
        float4 B3 = *(const float4*)(xrow + 76);
        xrow += 96;
        float dBu = dl * uv;
        ds += dl;
        float Bv[16] = {B0.x,B0.y,B0.z,B0.w, B1.x,B1.y,B1.z,B1.w,
                        B2.x,B2.y,B2.z,B2.w, B3.x,B3.y,B3.z,B3.w};
        #pragma unroll
        for (int n = 0; n < 16; ++n)
            h[n] = __expf(dl * Ac[n]) * h[n] + dBu * Bv[n];
    }
    float4* hf = (float4*)&hfin[(size_t)t * 16];
    #pragma unroll
    for (int i = 0; i < 4; ++i)
        hf[i] = (float4){h[4*i+0], h[4*i+1], h[4*i+2], h[4*i+3]};
    dsum[t] = ds;
}

__global__ __launch_bounds__(256) void scan_p2_kernel(
        const float* __restrict__ A_log, const float* __restrict__ dsum,
        const float* __restrict__ hfin, float* __restrict__ hin) {
    int t = blockIdx.x * 256 + threadIdx.x;
    int n = t & 15;
    int d = (t >> 4) & (HALF - 1);
    int b = t >> 14;
    float Ac = -__expf(A_log[d * DSTATE + n]);
    float h = 0.f;
    for (int ch = 0; ch < NCH; ++ch) {
        size_t chain = ((size_t)(b * NCH + ch) * HALF) + d;
        hin[chain * 16 + n] = h;
        float ds = dsum[chain];
        h = __expf(Ac * ds) * h + hfin[chain * 16 + n];
    }
}

__global__ __launch_bounds__(256) void scan_p3_kernel(
        const float* __restrict__ delta, const u16* __restrict__ u_bf,
        const float* __restrict__ x_dbl, const float* __restrict__ A_log,
        const float* __restrict__ Dp, const float* __restrict__ hin,
        u16* __restrict__ ycat) {
    int t  = blockIdx.x * 256 + threadIdx.x;
    int d  = t & (HALF - 1);
    int ch = (t >> 10) & (NCH - 1);
    int b  = t >> 16;
    float Ac[16], h[16];
    #pragma unroll
    for (int i = 0; i < 4; ++i) {
        float4 a  = *(const float4*)&A_log[d * DSTATE + i * 4];
        float4 hv = *(const float4*)&hin[(size_t)t * 16 + i * 4];
        Ac[4*i+0] = -__expf(a.x); Ac[4*i+1] = -__expf(a.y);
        Ac[4*i+2] = -__expf(a.z); Ac[4*i+3] = -__expf(a.w);
        h[4*i+0] = hv.x; h[4*i+1] = hv.y; h[4*i+2] = hv.z; h[4*i+3] = hv.w;
    }
    float Dv = Dp[d];
    int l0 = b * SEQ + ch * CL;
    size_t off = (size_t)l0 * HALF + d;
    const float* xrow = x_dbl + (size_t)l0 * 96;
    u16* yp = ycat + (size_t)l0 * DINNER + d;
    #pragma unroll 4
    for (int l = 0; l < CL; ++l) {
        float dl = delta[off];
        float uv = bf2f(u_bf[off]);
        off += HALF;
        float4 B0 = *(const float4*)(xrow + 64);
        float4 B1 = *(const float4*)(xrow + 68);
        float4 B2 = *(const float4*)(xrow + 72);
        float4 B3 = *(const float4*)(xrow + 76);
        float4 C0 = *(const float4*)(xrow + 80);
        float4 C1 = *(const float4*)(xrow + 84);
        float4 C2 = *(const float4*)(xrow + 88);
        float4 C3 = *(const float4*)(xrow + 92);
        xrow += 96;
        float dBu = dl * uv;
        float Bv[16] = {B0.x,B0.y,B0.z,B0.w, B1.x,B1.y,B1.z,B1.w,
                        B2.x,B2.y,B2.z,B2.w, B3.x,B3.y,B3.z,B3.w};
        float Cv[16] = {C0.x,C0.y,C0.z,C0.w, C1.x,C1.y,C1.z,C1.w,
                        C2.x,C2.y,C2.z,C2.w, C3.x,C3.y,C3.z,C3.w};
        float y = uv * Dv;
        #pragma unroll
        for (int n = 0; n < 16; ++n) {
            h[n] = __expf(dl * Ac[n]) * h[n] + dBu * Bv[n];
            y += h[n] * Cv[n];
        }
        *yp = f2bf(y);
        yp += DINNER;
    }
}

// ---------------- host-side orchestration ----------------
extern "C" void kernel_launch(void* const* d_in, const int* in_sizes, int n_in,
                              void* d_out, int out_size, void* d_ws, size_t ws_size,
                              hipStream_t stream) {
    const float* x         = (const float*)d_in[0];
    const float* ln1_g     = (const float*)d_in[1];
    const float* ln1_b     = (const float*)d_in[2];
    const float* in_proj_w = (const float*)d_in[3];
    const float* conv_x_w  = (const float*)d_in[4];
    const float* conv_x_b  = (const float*)d_in[5];
    const float* conv_z_w  = (const float*)d_in[6];
    const float* conv_z_b  = (const float*)d_in[7];
    const float* x_proj_w  = (const float*)d_in[8];
    const float* dt_proj_w = (const float*)d_in[9];
    const float* dt_proj_b = (const float*)d_in[10];
    const float* A_log     = (const float*)d_in[11];
    const float* Dp        = (const float*)d_in[12];
    const float* out_proj_w= (const float*)d_in[13];
    const float* ln2_g     = (const float*)d_in[14];
    const float* ln2_b     = (const float*)d_in[15];
    const float* mlp_w1    = (const float*)d_in[16];
    const float* mlp_b1    = (const float*)d_in[17];
    const float* mlp_w2    = (const float*)d_in[18];
    const float* mlp_b2    = (const float*)d_in[19];
    float* out = (float*)d_out;

    char* p = (char*)d_ws;
    auto alloc = [&](size_t bytes) {
        char* r = p; p += (bytes + 255) & ~(size_t)255; return r;
    };
    u16*   w_in   = (u16*)  alloc((size_t)DINNER * DIMD * 2);
    u16*   w_xp   = (u16*)  alloc((size_t)96 * HALF * 2);
    u16*   w_dt   = (u16*)  alloc((size_t)HALF * DTRANK * 2);
    u16*   w_out  = (u16*)  alloc((size_t)DIMD * DINNER * 2);
    u16*   w_m1   = (u16*)  alloc((size_t)MLPD * DIMD * 2);
    u16*   w_m2   = (u16*)  alloc((size_t)DIMD * MLPD * 2);
    u16*   xn_bf  = (u16*)  alloc((size_t)NTOK * DIMD * 2);
    u16*   xz_bf  = (u16*)  alloc((size_t)NTOK * DINNER * 2);
    u16*   u_bf   = (u16*)  alloc((size_t)NTOK * HALF * 2);
    u16*   ycat   = (u16*)  alloc((size_t)NTOK * DINNER * 2);
    float* x_dbl  = (float*)alloc((size_t)NTOK * 96 * 4);
    u16*   xdbl_bf= (u16*)  alloc((size_t)NTOK * 96 * 2);
    float* delta  = (float*)alloc((size_t)NTOK * HALF * 4);
    float* x2     = (float*)alloc((size_t)NTOK * DIMD * 4);
    u16*   ln2_bf = (u16*)  alloc((size_t)NTOK * DIMD * 2);
    u16*   mlp_h  = (u16*)  alloc((size_t)NTOK * MLPD * 2);    // 32 MB
    // scan scratch aliases mlp_h (dead until mlp1):
    float* hfin = (float*)mlp_h;
    float* hin  = hfin + (size_t)BSZ * NCH * HALF * DSTATE;
    float* dsum = hin  + (size_t)BSZ * NCH * HALF * DSTATE;

    // fused LN1 + weight conversions
    cvtln_kernel<<<NTOK + CVT_BLOCKS, 256, 0, stream>>>(
        x, ln1_g, ln1_b, xn_bf,
        in_proj_w, w_in, x_proj_w, w_xp, dt_proj_w, w_dt,
        out_proj_w, w_out, mlp_w1, w_m1, mlp_w2, w_m2);

    // in_proj: xz_bf[4096,2048] = xn @ W^T (bf16 out, 2-phase 128x128)
    gemm128_kernel<5,128,1><<<dim3(NTOK/128, DINNER/128), 256, 0, stream>>>(
        xn_bf, DIMD, w_in, DIMD, DINNER, nullptr, nullptr,
        nullptr, nullptr, nullptr, nullptr, xz_bf);

    // depthwise conv + silu
    conv_silu_kernel<<<dim3(HALF/256, NTOK/8), 256, 0, stream>>>(
        xz_bf, conv_x_w, conv_x_b, conv_z_w, conv_z_b, u_bf, ycat);

    // x_proj
    gemm_small_kernel<<<dim3(NTOK/32, 96/16), 256, 0, stream>>>(
        u_bf, HALF, w_xp, HALF, 96, x_dbl, xdbl_bf);

    // dt_proj: delta = softplus(dt @ W^T + b)  (BK=64, single K-slab)
    gemm64_kernel<1><<<dim3(NTOK/128, HALF/64), 256, 0, stream>>>(
        xdbl_bf, 96, w_dt, DTRANK, HALF, dt_proj_b, nullptr, delta);

    // chunk-parallel scan
    scan_p1_kernel<<<(BSZ*NCH*HALF)/256, 256, 0, stream>>>(
        delta, u_bf, x_dbl, A_log, hfin, dsum);
    scan_p2_kernel<<<(BSZ*HALF*DSTATE)/256, 256, 0, stream>>>(
        A_log, dsum, hfin, hin);
    scan_p3_kernel<<<(BSZ*NCH*HALF)/256, 256, 0, stream>>>(
        delta, u_bf, x_dbl, A_log, Dp, hin, ycat);

    // out_proj (BK=64, fused residual): x2 = ycat @ W^T + x
    gemm64_kernel<3><<<dim3(NTOK/128, DIMD/64), 256, 0, stream>>>(
        ycat, DINNER, w_out, DINNER, DIMD, nullptr, x, x2);

    // slim LN2: ln2_bf = LN(x2)
    ln2_kernel<<<NTOK, 256, 0, stream>>>(x2, ln2_g, ln2_b, ln2_bf);

    // MLP1: 8-phase 256^2 + swizzle: gelu(ln2 @ W1^T + b1) -> bf16
    gemm256_kernel<2,1><<<dim3(NTOK/256, MLPD/256, 1), 512, 0, stream>>>(
        ln2_bf, DIMD, w_m1, DIMD, MLPD, mlp_b1,
        nullptr, nullptr, nullptr, nullptr, mlp_h);

    // MLP2 (BK=64, fused bias+residual): out = mlp_h @ W2^T + b2 + x2
    gemm64_kernel<4><<<dim3(NTOK/128, DIMD/64), 256, 0, stream>>>(
        mlp_h, MLPD, w_m2, MLPD, DIMD, mlp_b2, x2, out);
}